// Round 1
// baseline (4880.607 us; speedup 1.0000x reference)
//
#include <hip/hip_runtime.h>
#include <math.h>

// EncoderLayer on MI355X — Round 0: correct fp32 baseline.
// Pipeline: 3x GEMM(QKV) -> flash-attn -> GEMM(out proj) -> add+LN ->
//           GEMM(FFN1,relu) -> GEMM(FFN2) -> add+LN (in place on d_out).
// All fp32. Next rounds: bf16 MFMA for the GEMMs (240 GFLOP of 275 total).

#define D_MODEL 1024
#define N_HEADS 16
#define DK      64
#define D_FF    4096
#define BATCH   4
#define SEQ     2048
#define NTOK    (BATCH * SEQ)   // 8192
#define LN_EPS  1e-5f

// ---------------------------------------------------------------------------
// GEMM: C[M,N] = A[M,K] @ B[K,N] + bias[N], optional ReLU.
// 64x64 tile, BK=16, 256 threads, 4x4 micro-tile/thread.
// M,N,K must be multiples of 64/64/16 (true for all shapes here).
// ---------------------------------------------------------------------------
template <bool RELU>
__global__ __launch_bounds__(256, 4) void gemm_bias_kernel(
    const float* __restrict__ A, const float* __restrict__ B,
    const float* __restrict__ bias, float* __restrict__ C,
    int M, int N, int K)
{
    __shared__ float As[16][68];   // stored transposed: As[k][m]; 68 = pad, float4-aligned
    __shared__ float Bs[16][68];   // Bs[k][n]

    const int tid = threadIdx.x;
    const int tx  = tid & 15;      // output col group
    const int ty  = tid >> 4;      // output row group
    const int m0  = blockIdx.y << 6;
    const int n0  = blockIdx.x << 6;

    // staging indices
    const int arow = tid >> 2;           // 0..63
    const int acol = (tid & 3) << 2;     // 0,4,8,12
    const int brow = tid >> 4;           // 0..15
    const int bcol = (tid & 15) << 2;    // 0..60

    const float* Aptr = A + (size_t)(m0 + arow) * K + acol;
    const float* Bptr = B + (size_t)brow * N + n0 + bcol;

    float acc[4][4] = {};

    for (int k0 = 0; k0 < K; k0 += 16) {
        const float4 av = *(const float4*)(Aptr + k0);
        const float4 bv = *(const float4*)(Bptr + (size_t)k0 * N);
        __syncthreads();
        As[acol + 0][arow] = av.x;
        As[acol + 1][arow] = av.y;
        As[acol + 2][arow] = av.z;
        As[acol + 3][arow] = av.w;
        *(float4*)&Bs[brow][bcol] = bv;
        __syncthreads();
#pragma unroll
        for (int k = 0; k < 16; ++k) {
            const float4 a = *(const float4*)&As[k][ty << 2];
            const float4 b = *(const float4*)&Bs[k][tx << 2];
            const float ar[4] = {a.x, a.y, a.z, a.w};
            const float br[4] = {b.x, b.y, b.z, b.w};
#pragma unroll
            for (int i = 0; i < 4; ++i)
#pragma unroll
                for (int j = 0; j < 4; ++j)
                    acc[i][j] = fmaf(ar[i], br[j], acc[i][j]);
        }
    }

    const float4 b4 = *(const float4*)&bias[n0 + (tx << 2)];
#pragma unroll
    for (int i = 0; i < 4; ++i) {
        float4 o;
        o.x = acc[i][0] + b4.x;
        o.y = acc[i][1] + b4.y;
        o.z = acc[i][2] + b4.z;
        o.w = acc[i][3] + b4.w;
        if (RELU) {
            o.x = fmaxf(o.x, 0.f); o.y = fmaxf(o.y, 0.f);
            o.z = fmaxf(o.z, 0.f); o.w = fmaxf(o.w, 0.f);
        }
        *(float4*)&C[(size_t)(m0 + (ty << 2) + i) * N + n0 + (tx << 2)] = o;
    }
}

// ---------------------------------------------------------------------------
// Flash attention (fp32, online softmax). One thread per query row.
// Q/K/V layout: [b*SEQ + s][D_MODEL], head h = cols h*64..h*64+63.
// grid = (BATCH*N_HEADS, SEQ/256), block = 256.
// ---------------------------------------------------------------------------
__global__ __launch_bounds__(256, 2) void attn_kernel(
    const float* __restrict__ Q, const float* __restrict__ Km,
    const float* __restrict__ Vm, float* __restrict__ O)
{
    const int bh   = blockIdx.x;
    const int b    = bh >> 4;
    const int h    = bh & 15;
    const int qrow = (blockIdx.y << 8) + threadIdx.x;   // 0..2047
    const size_t base = (size_t)b * SEQ * D_MODEL + (size_t)h * DK;

    __shared__ float Ks[64][DK];
    __shared__ float Vs[64][DK];

    // q row in registers, pre-scaled by 1/sqrt(dk) = 0.125
    float4 qr[16];
#pragma unroll
    for (int i = 0; i < 16; ++i) {
        float4 t = *(const float4*)&Q[base + (size_t)qrow * D_MODEL + (i << 2)];
        qr[i].x = t.x * 0.125f; qr[i].y = t.y * 0.125f;
        qr[i].z = t.z * 0.125f; qr[i].w = t.w * 0.125f;
    }
    float4 o[16];
#pragma unroll
    for (int i = 0; i < 16; ++i) o[i] = make_float4(0.f, 0.f, 0.f, 0.f);
    float mrun = -1e30f, lrun = 0.f;

    const int lr = threadIdx.x >> 2;          // staging row 0..63
    const int lc = (threadIdx.x & 3) << 4;    // staging col 0,16,32,48

    for (int kv0 = 0; kv0 < SEQ; kv0 += 64) {
        __syncthreads();
        const float* kg = &Km[base + (size_t)(kv0 + lr) * D_MODEL + lc];
        const float* vg = &Vm[base + (size_t)(kv0 + lr) * D_MODEL + lc];
#pragma unroll
        for (int t = 0; t < 4; ++t) {
            *(float4*)&Ks[lr][lc + (t << 2)] = *(const float4*)&kg[t << 2];
            *(float4*)&Vs[lr][lc + (t << 2)] = *(const float4*)&vg[t << 2];
        }
        __syncthreads();

        for (int j0 = 0; j0 < 64; j0 += 16) {
            float s[16];
#pragma unroll
            for (int jj = 0; jj < 16; ++jj) {
                float ax = 0.f, ay = 0.f, az = 0.f, aw = 0.f;
#pragma unroll
                for (int i = 0; i < 16; ++i) {
                    const float4 kk = *(const float4*)&Ks[j0 + jj][i << 2];
                    ax = fmaf(qr[i].x, kk.x, ax);
                    ay = fmaf(qr[i].y, kk.y, ay);
                    az = fmaf(qr[i].z, kk.z, az);
                    aw = fmaf(qr[i].w, kk.w, aw);
                }
                s[jj] = (ax + ay) + (az + aw);
            }
            float tmax = s[0];
#pragma unroll
            for (int jj = 1; jj < 16; ++jj) tmax = fmaxf(tmax, s[jj]);
            const float mnew = fmaxf(mrun, tmax);
            const float corr = __expf(mrun - mnew);
            lrun *= corr;
#pragma unroll
            for (int i = 0; i < 16; ++i) {
                o[i].x *= corr; o[i].y *= corr; o[i].z *= corr; o[i].w *= corr;
            }
            mrun = mnew;
#pragma unroll
            for (int jj = 0; jj < 16; ++jj) {
                const float p = __expf(s[jj] - mnew);
                lrun += p;
#pragma unroll
                for (int i = 0; i < 16; ++i) {
                    const float4 vv = *(const float4*)&Vs[j0 + jj][i << 2];
                    o[i].x = fmaf(p, vv.x, o[i].x);
                    o[i].y = fmaf(p, vv.y, o[i].y);
                    o[i].z = fmaf(p, vv.z, o[i].z);
                    o[i].w = fmaf(p, vv.w, o[i].w);
                }
            }
        }
    }

    const float inv = 1.0f / lrun;
#pragma unroll
    for (int i = 0; i < 16; ++i) {
        const float4 ov = make_float4(o[i].x * inv, o[i].y * inv,
                                      o[i].z * inv, o[i].w * inv);
        *(float4*)&O[base + (size_t)qrow * D_MODEL + (i << 2)] = ov;
    }
}

// ---------------------------------------------------------------------------
// out = LayerNorm(X + Y) * gamma + beta. One block (256 thr) per row of 1024.
// Safe to call with O == Y (all reads complete before the post-reduce writes).
// ---------------------------------------------------------------------------
__global__ __launch_bounds__(256) void add_ln_kernel(
    const float* __restrict__ X, const float* __restrict__ Y,
    const float* __restrict__ gamma, const float* __restrict__ beta,
    float* __restrict__ O)
{
    const int row = blockIdx.x;
    const int i0  = threadIdx.x << 2;
    const float4 xv = *(const float4*)(X + (size_t)row * D_MODEL + i0);
    const float4 yv = *(const float4*)(Y + (size_t)row * D_MODEL + i0);
    const float4 v  = make_float4(xv.x + yv.x, xv.y + yv.y,
                                  xv.z + yv.z, xv.w + yv.w);

    float s1 = v.x + v.y + v.z + v.w;
    float s2 = v.x * v.x + v.y * v.y + v.z * v.z + v.w * v.w;
#pragma unroll
    for (int off = 32; off > 0; off >>= 1) {
        s1 += __shfl_xor(s1, off, 64);
        s2 += __shfl_xor(s2, off, 64);
    }
    __shared__ float red[8];
    const int wid = threadIdx.x >> 6;
    if ((threadIdx.x & 63) == 0) { red[wid] = s1; red[wid + 4] = s2; }
    __syncthreads();
    s1 = red[0] + red[1] + red[2] + red[3];
    s2 = red[4] + red[5] + red[6] + red[7];

    const float mu   = s1 * (1.0f / D_MODEL);
    const float var  = s2 * (1.0f / D_MODEL) - mu * mu;
    const float rstd = rsqrtf(var + LN_EPS);

    const float4 g  = *(const float4*)(gamma + i0);
    const float4 bb = *(const float4*)(beta + i0);
    float4 ov;
    ov.x = (v.x - mu) * rstd * g.x + bb.x;
    ov.y = (v.y - mu) * rstd * g.y + bb.y;
    ov.z = (v.z - mu) * rstd * g.z + bb.z;
    ov.w = (v.w - mu) * rstd * g.w + bb.w;
    *(float4*)(O + (size_t)row * D_MODEL + i0) = ov;
}

// ---------------------------------------------------------------------------
extern "C" void kernel_launch(void* const* d_in, const int* in_sizes, int n_in,
                              void* d_out, int out_size, void* d_ws, size_t ws_size,
                              hipStream_t stream)
{
    const float* x     = (const float*)d_in[0];
    const float* Wq    = (const float*)d_in[1];
    const float* bq    = (const float*)d_in[2];
    const float* Wk    = (const float*)d_in[3];
    const float* bk    = (const float*)d_in[4];
    const float* Wv    = (const float*)d_in[5];
    const float* bv    = (const float*)d_in[6];
    const float* Wo    = (const float*)d_in[7];
    const float* bo    = (const float*)d_in[8];
    const float* W1    = (const float*)d_in[9];
    const float* b1    = (const float*)d_in[10];
    const float* W2    = (const float*)d_in[11];
    const float* b2    = (const float*)d_in[12];
    const float* g1    = (const float*)d_in[13];
    const float* beta1 = (const float*)d_in[14];
    const float* g2    = (const float*)d_in[15];
    const float* beta2 = (const float*)d_in[16];
    float* out = (float*)d_out;

    // workspace: 5 slots of NTOK*D_MODEL floats = 167.8 MB total
    const size_t SLOT = (size_t)NTOK * D_MODEL;
    float* q   = (float*)d_ws;
    float* k   = q + SLOT;
    float* v   = k + SLOT;
    float* ctx = v + SLOT;
    float* y1  = ctx + SLOT;
    float* x2  = q;       // reuse: q dead after attention
    float* h1  = k;       // spans k,v,ctx,y1 = NTOK*D_FF floats

    const dim3 blk(256);
    const dim3 gD(D_MODEL / 64, NTOK / 64);   // N=1024 GEMMs
    const dim3 gF(D_FF / 64,   NTOK / 64);    // N=4096 GEMM

    // QKV projections
    gemm_bias_kernel<false><<<gD, blk, 0, stream>>>(x, Wq, bq, q, NTOK, D_MODEL, D_MODEL);
    gemm_bias_kernel<false><<<gD, blk, 0, stream>>>(x, Wk, bk, k, NTOK, D_MODEL, D_MODEL);
    gemm_bias_kernel<false><<<gD, blk, 0, stream>>>(x, Wv, bv, v, NTOK, D_MODEL, D_MODEL);

    // attention
    attn_kernel<<<dim3(BATCH * N_HEADS, SEQ / 256), blk, 0, stream>>>(q, k, v, ctx);

    // output projection
    gemm_bias_kernel<false><<<gD, blk, 0, stream>>>(ctx, Wo, bo, y1, NTOK, D_MODEL, D_MODEL);

    // x2 = LN(x + y1)
    add_ln_kernel<<<dim3(NTOK), blk, 0, stream>>>(x, y1, g1, beta1, x2);

    // FFN
    gemm_bias_kernel<true ><<<gF, blk, 0, stream>>>(x2, W1, b1, h1, NTOK, D_FF, D_MODEL);
    gemm_bias_kernel<false><<<gD, blk, 0, stream>>>(h1, W2, b2, out, NTOK, D_MODEL, D_FF);

    // out = LN(x2 + out)  (in place)
    add_ln_kernel<<<dim3(NTOK), blk, 0, stream>>>(x2, out, g2, beta2, out);

    (void)in_sizes; (void)n_in; (void)out_size; (void)ws_size;
}

// Round 2
// 646.050 us; speedup vs baseline: 7.5545x; 7.5545x over previous
//
#include <hip/hip_runtime.h>
#include <math.h>
#include <stdint.h>

// EncoderLayer on MI355X — Round 1: bf16 MFMA everywhere.
// GEMMs: m97-style 128x128 tile, BK=32, global_load_lds(16B), B^T weights.
// Attention: flash-style MFMA, K/V staged in LDS (V transposed), P via LDS.

#define D_MODEL 1024
#define N_HEADS 16
#define DKH     64
#define D_FF    4096
#define BATCH   4
#define SEQ     2048
#define NTOK    (BATCH * SEQ)   // 8192
#define LN_EPS  1e-5f

typedef unsigned short u16;
typedef __attribute__((ext_vector_type(8))) short bf16x8;
typedef __attribute__((ext_vector_type(4))) float f32x4;

__device__ __forceinline__ u16 f2bf(float f) {
    union { float f; uint32_t u; } c; c.f = f;
    return (u16)((c.u + 0x7FFFu + ((c.u >> 16) & 1u)) >> 16);   // RNE
}
__device__ __forceinline__ float bf2f(u16 h) {
    union { uint32_t u; float f; } c; c.u = ((uint32_t)h) << 16;
    return c.f;
}

// async global->LDS, 16B per lane; lds must be wave-uniform (HW writes base+lane*16)
__device__ __forceinline__ void gload16(const u16* g, u16* lds) {
    __builtin_amdgcn_global_load_lds(
        (const __attribute__((address_space(1))) uint32_t*)g,
        (__attribute__((address_space(3))) uint32_t*)(uintptr_t)lds,
        16, 0, 0);
}

// ---------------------------------------------------------------------------
// bf16 GEMM: C[M,N] = A[M,K] @ Bt[N,K]^T + bias, optional ReLU.
// 128x128 tile, BK=32, 256 thr = 4 waves (2x2), 4x4 16x16x32 MFMA frags/wave.
// ---------------------------------------------------------------------------
__device__ __forceinline__ void store_out(float* p, float v) { *p = v; }
__device__ __forceinline__ void store_out(u16* p, float v)   { *p = f2bf(v); }

template <bool RELU, typename OutT>
__global__ __launch_bounds__(256, 2) void gemm_bf16_kernel(
    const u16* __restrict__ A, const u16* __restrict__ Bt,
    const float* __restrict__ bias, OutT* __restrict__ C,
    int M, int N, int K)
{
    __shared__ u16 Alds[128 * 32];   // [row][k] linear, 64B rows (gload_lds needs linear)
    __shared__ u16 Blds[128 * 32];   // [ncol][k]

    const int tid  = threadIdx.x;
    const int wave = tid >> 6;
    const int lane = tid & 63;
    const int lo   = lane & 15;
    const int hi   = lane >> 4;
    const int m0   = blockIdx.y << 7;
    const int n0   = blockIdx.x << 7;
    const int wr   = wave >> 1;      // 0..1
    const int wc   = wave & 1;       // 0..1

    // staging: wave w fills LDS rows [w*32, w*32+32) of both tiles
    const int srow = wave * 32 + (lane >> 2);
    const int scol = (lane & 3) * 8;
    const u16* Ag = A  + (size_t)(m0 + srow) * K + scol;
    const u16* Bg = Bt + (size_t)(n0 + srow) * K + scol;
    u16* AldsW = Alds + wave * 1024;   // bytes w*2048
    u16* BldsW = Blds + wave * 1024;

    f32x4 acc[4][4];
#pragma unroll
    for (int i = 0; i < 4; ++i)
#pragma unroll
        for (int j = 0; j < 4; ++j)
#pragma unroll
            for (int r = 0; r < 4; ++r) acc[i][j][r] = 0.f;

    for (int k0 = 0; k0 < K; k0 += 32) {
        __syncthreads();                       // prev reads done before overwrite
        gload16(Ag + k0,                 AldsW);
        gload16(Ag + k0 + 16 * (size_t)K, AldsW + 512);
        gload16(Bg + k0,                 BldsW);
        gload16(Bg + k0 + 16 * (size_t)K, BldsW + 512);
        __syncthreads();                       // compiler drains vmcnt before barrier

        bf16x8 a[4], b[4];
#pragma unroll
        for (int i = 0; i < 4; ++i) {
            a[i] = *(const bf16x8*)&Alds[(wr * 64 + i * 16 + lo) * 32 + hi * 8];
            b[i] = *(const bf16x8*)&Blds[(wc * 64 + i * 16 + lo) * 32 + hi * 8];
        }
#pragma unroll
        for (int i = 0; i < 4; ++i)
#pragma unroll
            for (int j = 0; j < 4; ++j)
                acc[i][j] = __builtin_amdgcn_mfma_f32_16x16x32_bf16(
                                a[i], b[j], acc[i][j], 0, 0, 0);
    }

    // epilogue: C/D layout col=lane&15, row=(lane>>4)*4+reg (verified m89/m91)
    const int crow = m0 + wr * 64 + hi * 4;
    const int ccol = n0 + wc * 64 + lo;
#pragma unroll
    for (int j = 0; j < 4; ++j) {
        const float bj = bias[ccol + j * 16];
#pragma unroll
        for (int i = 0; i < 4; ++i)
#pragma unroll
            for (int r = 0; r < 4; ++r) {
                float v = acc[i][j][r] + bj;
                if (RELU) v = fmaxf(v, 0.f);
                store_out(&C[(size_t)(crow + i * 16 + r) * N + ccol + j * 16], v);
            }
    }
}

// ---------------------------------------------------------------------------
// Flash attention, bf16 MFMA. Block = (b,h) x 64 q-rows; 4 waves x 16 rows.
// KV tile 64. K_lds row-major [kv][dk]; V_lds transposed [dk][kv]; P via LDS.
// ---------------------------------------------------------------------------
__global__ __launch_bounds__(256, 2) void attn_mfma_kernel(
    const u16* __restrict__ Q, const u16* __restrict__ Km,
    const u16* __restrict__ Vm, u16* __restrict__ O)
{
    constexpr int LROW = 72;                  // u16/row (144B): 16B-aligned, conflict-light
    __shared__ u16 Klds[64 * LROW];
    __shared__ u16 Vlds[64 * LROW];
    __shared__ u16 Plds[4][16 * LROW];

    const int tid  = threadIdx.x;
    const int wave = tid >> 6;
    const int lane = tid & 63;
    const int lo   = lane & 15;
    const int hi   = lane >> 4;
    const int b    = blockIdx.x >> 4;
    const int h    = blockIdx.x & 15;
    const int q0   = blockIdx.y * 64 + wave * 16;
    const size_t base = (size_t)b * SEQ * D_MODEL + (size_t)h * DKH;

    // Q fragments in regs (A-operand: row=lane&15, k contiguous per lane)
    bf16x8 qf[2];
#pragma unroll
    for (int f = 0; f < 2; ++f)
        qf[f] = *(const bf16x8*)&Q[base + (size_t)(q0 + lo) * D_MODEL + f * 32 + hi * 8];

    f32x4 oacc[4];
    float mrun[4], lrun[4];
#pragma unroll
    for (int g = 0; g < 4; ++g)
#pragma unroll
        for (int r = 0; r < 4; ++r) oacc[g][r] = 0.f;
#pragma unroll
    for (int r = 0; r < 4; ++r) { mrun[r] = -1e30f; lrun[r] = 0.f; }

    const int skv = tid >> 3;          // 0..31: kv row staged by this thread
    const int sc  = (tid & 7) * 8;     // dk offset, 8 bf16 = 16B

    for (int kv0 = 0; kv0 < SEQ; kv0 += 64) {
        __syncthreads();
        // K tile: row-major [kv][dk]
#pragma unroll
        for (int p = 0; p < 2; ++p) {
            const int r = skv + p * 32;
            *(int4*)&Klds[r * LROW + sc] =
                *(const int4*)&Km[base + (size_t)(kv0 + r) * D_MODEL + sc];
        }
        // V tile transposed: [dk][kv]
#pragma unroll
        for (int p = 0; p < 2; ++p) {
            const int kv = skv + p * 32;
            alignas(16) u16 e[8];
            *(int4*)e = *(const int4*)&Vm[base + (size_t)(kv0 + kv) * D_MODEL + sc];
#pragma unroll
            for (int j = 0; j < 8; ++j) Vlds[(sc + j) * LROW + kv] = e[j];
        }
        __syncthreads();

        // S = Q K^T  (16 x 64), scaled by 1/sqrt(64)
        f32x4 s[4];
#pragma unroll
        for (int g = 0; g < 4; ++g) {
#pragma unroll
            for (int r = 0; r < 4; ++r) s[g][r] = 0.f;
            const bf16x8 k0v = *(const bf16x8*)&Klds[(g * 16 + lo) * LROW + hi * 8];
            const bf16x8 k1v = *(const bf16x8*)&Klds[(g * 16 + lo) * LROW + 32 + hi * 8];
            s[g] = __builtin_amdgcn_mfma_f32_16x16x32_bf16(qf[0], k0v, s[g], 0, 0, 0);
            s[g] = __builtin_amdgcn_mfma_f32_16x16x32_bf16(qf[1], k1v, s[g], 0, 0, 0);
            s[g] = s[g] * 0.125f;
        }

        // online softmax (rows hi*4+r; cols spread over 16 lanes x 4 groups)
        float lsum[4];
#pragma unroll
        for (int r = 0; r < 4; ++r) {
            float tm = fmaxf(fmaxf(s[0][r], s[1][r]), fmaxf(s[2][r], s[3][r]));
#pragma unroll
            for (int m = 1; m < 16; m <<= 1) tm = fmaxf(tm, __shfl_xor(tm, m, 64));
            const float mnew = fmaxf(mrun[r], tm);
            const float corr = __expf(mrun[r] - mnew);
            mrun[r] = mnew;
            float ls = 0.f;
#pragma unroll
            for (int g = 0; g < 4; ++g) {
                const float p = __expf(s[g][r] - mnew);
                s[g][r] = p;
                ls += p;
            }
#pragma unroll
            for (int m = 1; m < 16; m <<= 1) ls += __shfl_xor(ls, m, 64);
            lrun[r] = lrun[r] * corr + ls;
            lsum[r] = corr;
        }
#pragma unroll
        for (int g = 0; g < 4; ++g)
#pragma unroll
            for (int r = 0; r < 4; ++r) oacc[g][r] *= lsum[r];

        // P -> LDS (bf16), per-wave region; intra-wave visibility via lgkmcnt
        u16* Pw = Plds[wave];
#pragma unroll
        for (int g = 0; g < 4; ++g)
#pragma unroll
            for (int r = 0; r < 4; ++r)
                Pw[(hi * 4 + r) * LROW + g * 16 + lo] = f2bf(s[g][r]);
        asm volatile("s_waitcnt lgkmcnt(0)" ::: "memory");
        __builtin_amdgcn_sched_barrier(0);

        // O += P V  (A-frag from Plds, B-frag from transposed Vlds; same k-map)
        bf16x8 pf[2];
#pragma unroll
        for (int f = 0; f < 2; ++f)
            pf[f] = *(const bf16x8*)&Pw[lo * LROW + f * 32 + hi * 8];
#pragma unroll
        for (int g = 0; g < 4; ++g) {
            const bf16x8 v0 = *(const bf16x8*)&Vlds[(g * 16 + lo) * LROW + hi * 8];
            const bf16x8 v1 = *(const bf16x8*)&Vlds[(g * 16 + lo) * LROW + 32 + hi * 8];
            oacc[g] = __builtin_amdgcn_mfma_f32_16x16x32_bf16(pf[0], v0, oacc[g], 0, 0, 0);
            oacc[g] = __builtin_amdgcn_mfma_f32_16x16x32_bf16(pf[1], v1, oacc[g], 0, 0, 0);
        }
    }

    float inv[4];
#pragma unroll
    for (int r = 0; r < 4; ++r) inv[r] = 1.f / lrun[r];
#pragma unroll
    for (int g = 0; g < 4; ++g)
#pragma unroll
        for (int r = 0; r < 4; ++r)
            O[base + (size_t)(q0 + hi * 4 + r) * D_MODEL + g * 16 + lo] =
                f2bf(oacc[g][r] * inv[r]);
}

// ---------------------------------------------------------------------------
// W[K][N] f32 -> Wt[N][K] bf16 (tiled 32x32 transpose)
// ---------------------------------------------------------------------------
__global__ __launch_bounds__(256) void transpose_w_kernel(
    const float* __restrict__ W, u16* __restrict__ Wt, int K, int N)
{
    __shared__ float t[32][33];
    const int n0 = blockIdx.x << 5;
    const int k0 = blockIdx.y << 5;
    const int tx = threadIdx.x & 31;
    const int ty = threadIdx.x >> 5;   // 0..7
#pragma unroll
    for (int i = 0; i < 4; ++i)
        t[ty + i * 8][tx] = W[(size_t)(k0 + ty + i * 8) * N + n0 + tx];
    __syncthreads();
#pragma unroll
    for (int i = 0; i < 4; ++i)
        Wt[(size_t)(n0 + ty + i * 8) * K + k0 + tx] = f2bf(t[tx][ty + i * 8]);
}

// f32 -> bf16 bulk convert, 8 elems/thread
__global__ __launch_bounds__(256) void cvt_kernel(
    const float* __restrict__ src, u16* __restrict__ dst)
{
    const size_t i = ((size_t)blockIdx.x * 256 + threadIdx.x) * 8;
    const float4 a = *(const float4*)&src[i];
    const float4 b = *(const float4*)&src[i + 4];
    alignas(16) u16 e[8] = { f2bf(a.x), f2bf(a.y), f2bf(a.z), f2bf(a.w),
                             f2bf(b.x), f2bf(b.y), f2bf(b.z), f2bf(b.w) };
    *(int4*)&dst[i] = *(const int4*)e;
}

// ---------------------------------------------------------------------------
// out = LayerNorm(X + Y)*gamma + beta; mixed dtypes. One block per row.
// ---------------------------------------------------------------------------
__device__ __forceinline__ float4 ld4(const float* p) { return *(const float4*)p; }
__device__ __forceinline__ float4 ld4(const u16* p) {
    alignas(8) u16 e[4];
    *(uint2*)e = *(const uint2*)p;
    return make_float4(bf2f(e[0]), bf2f(e[1]), bf2f(e[2]), bf2f(e[3]));
}
__device__ __forceinline__ void st4(float* p, float4 v) { *(float4*)p = v; }
__device__ __forceinline__ void st4(u16* p, float4 v) {
    alignas(8) u16 e[4] = { f2bf(v.x), f2bf(v.y), f2bf(v.z), f2bf(v.w) };
    *(uint2*)p = *(const uint2*)e;
}

template <typename XT, typename YT, typename OT>
__global__ __launch_bounds__(256) void add_ln_kernel(
    const XT* __restrict__ X, const YT* __restrict__ Y,
    const float* __restrict__ gamma, const float* __restrict__ beta,
    OT* __restrict__ Out)
{
    const int row = blockIdx.x;
    const int i0  = threadIdx.x << 2;
    const float4 xv = ld4(X + (size_t)row * D_MODEL + i0);
    const float4 yv = ld4(Y + (size_t)row * D_MODEL + i0);
    const float4 v  = make_float4(xv.x + yv.x, xv.y + yv.y, xv.z + yv.z, xv.w + yv.w);

    float s1 = v.x + v.y + v.z + v.w;
    float s2 = v.x * v.x + v.y * v.y + v.z * v.z + v.w * v.w;
#pragma unroll
    for (int off = 32; off > 0; off >>= 1) {
        s1 += __shfl_xor(s1, off, 64);
        s2 += __shfl_xor(s2, off, 64);
    }
    __shared__ float red[8];
    const int wid = threadIdx.x >> 6;
    if ((threadIdx.x & 63) == 0) { red[wid] = s1; red[wid + 4] = s2; }
    __syncthreads();
    s1 = red[0] + red[1] + red[2] + red[3];
    s2 = red[4] + red[5] + red[6] + red[7];

    const float mu   = s1 * (1.0f / D_MODEL);
    const float var  = s2 * (1.0f / D_MODEL) - mu * mu;
    const float rstd = rsqrtf(var + LN_EPS);

    const float4 g  = *(const float4*)(gamma + i0);
    const float4 bb = *(const float4*)(beta + i0);
    float4 ov;
    ov.x = (v.x - mu) * rstd * g.x + bb.x;
    ov.y = (v.y - mu) * rstd * g.y + bb.y;
    ov.z = (v.z - mu) * rstd * g.z + bb.z;
    ov.w = (v.w - mu) * rstd * g.w + bb.w;
    st4(Out + (size_t)row * D_MODEL + i0, ov);
}

// ---------------------------------------------------------------------------
extern "C" void kernel_launch(void* const* d_in, const int* in_sizes, int n_in,
                              void* d_out, int out_size, void* d_ws, size_t ws_size,
                              hipStream_t stream)
{
    const float* x     = (const float*)d_in[0];
    const float* Wq    = (const float*)d_in[1];
    const float* bq    = (const float*)d_in[2];
    const float* Wk    = (const float*)d_in[3];
    const float* bk    = (const float*)d_in[4];
    const float* Wv    = (const float*)d_in[5];
    const float* bv    = (const float*)d_in[6];
    const float* Wo    = (const float*)d_in[7];
    const float* bo    = (const float*)d_in[8];
    const float* W1    = (const float*)d_in[9];
    const float* b1    = (const float*)d_in[10];
    const float* W2    = (const float*)d_in[11];
    const float* b2    = (const float*)d_in[12];
    const float* g1    = (const float*)d_in[13];
    const float* beta1 = (const float*)d_in[14];
    const float* g2    = (const float*)d_in[15];
    const float* beta2 = (const float*)d_in[16];
    float* out = (float*)d_out;

    // workspace (u16 units), ~126 MB total
    const size_t TOKD = (size_t)NTOK * D_MODEL;     // 8388608
    u16* xb  = (u16*)d_ws;
    u16* wqT = xb  + TOKD;
    u16* wkT = wqT + (size_t)D_MODEL * D_MODEL;
    u16* wvT = wkT + (size_t)D_MODEL * D_MODEL;
    u16* woT = wvT + (size_t)D_MODEL * D_MODEL;
    u16* w1T = woT + (size_t)D_MODEL * D_MODEL;
    u16* w2T = w1T + (size_t)D_MODEL * D_FF;
    u16* q   = w2T + (size_t)D_MODEL * D_FF;
    u16* k   = q   + TOKD;
    u16* v   = k   + TOKD;
    u16* ctx = v   + TOKD;
    u16* y1  = ctx + TOKD;
    u16* x2  = q;                 // q dead after attention
    u16* h1  = k;                 // spans k,v,ctx,y1 = NTOK*D_FF

    const dim3 blk(256);

    // conversions
    cvt_kernel<<<dim3(TOKD / 2048), blk, 0, stream>>>(x, xb);
    transpose_w_kernel<<<dim3(D_MODEL / 32, D_MODEL / 32), blk, 0, stream>>>(Wq, wqT, D_MODEL, D_MODEL);
    transpose_w_kernel<<<dim3(D_MODEL / 32, D_MODEL / 32), blk, 0, stream>>>(Wk, wkT, D_MODEL, D_MODEL);
    transpose_w_kernel<<<dim3(D_MODEL / 32, D_MODEL / 32), blk, 0, stream>>>(Wv, wvT, D_MODEL, D_MODEL);
    transpose_w_kernel<<<dim3(D_MODEL / 32, D_MODEL / 32), blk, 0, stream>>>(Wo, woT, D_MODEL, D_MODEL);
    transpose_w_kernel<<<dim3(D_FF / 32,   D_MODEL / 32), blk, 0, stream>>>(W1, w1T, D_MODEL, D_FF);
    transpose_w_kernel<<<dim3(D_MODEL / 32, D_FF / 32),   blk, 0, stream>>>(W2, w2T, D_FF, D_MODEL);

    const dim3 gD(D_MODEL / 128, NTOK / 128);   // (8, 64)
    const dim3 gF(D_FF / 128,   NTOK / 128);    // (32, 64)

    gemm_bf16_kernel<false, u16><<<gD, blk, 0, stream>>>(xb, wqT, bq, q, NTOK, D_MODEL, D_MODEL);
    gemm_bf16_kernel<false, u16><<<gD, blk, 0, stream>>>(xb, wkT, bk, k, NTOK, D_MODEL, D_MODEL);
    gemm_bf16_kernel<false, u16><<<gD, blk, 0, stream>>>(xb, wvT, bv, v, NTOK, D_MODEL, D_MODEL);

    attn_mfma_kernel<<<dim3(BATCH * N_HEADS, SEQ / 64), blk, 0, stream>>>(q, k, v, ctx);

    gemm_bf16_kernel<false, u16><<<gD, blk, 0, stream>>>(ctx, woT, bo, y1, NTOK, D_MODEL, D_MODEL);
    add_ln_kernel<float, u16, u16><<<dim3(NTOK), blk, 0, stream>>>(x, y1, g1, beta1, x2);

    gemm_bf16_kernel<true,  u16><<<gF, blk, 0, stream>>>(x2, w1T, b1, h1, NTOK, D_FF, D_MODEL);
    gemm_bf16_kernel<false, float><<<gD, blk, 0, stream>>>(h1, w2T, b2, out, NTOK, D_MODEL, D_FF);
    add_ln_kernel<u16, float, float><<<dim3(NTOK), blk, 0, stream>>>(x2, out, g2, beta2, out);

    (void)in_sizes; (void)n_in; (void)out_size; (void)ws_size;
}

// Round 3
// 550.881 us; speedup vs baseline: 8.8596x; 1.1728x over previous
//
#include <hip/hip_runtime.h>
#include <math.h>
#include <stdint.h>

// EncoderLayer on MI355X — Round 2: attention restructure.
// - fused QKV GEMM (N=3072), Q pre-scaled by 0.125*log2e in epilogue
// - attn: 32 q-rows/wave, K via global_load_lds + XOR-swizzled source,
//   V via 4x4 register transpose (vector LDS writes), exp2 softmax,
//   defer-max rescale, cvt_pk P->bf16.

#define D_MODEL 1024
#define N_HEADS 16
#define DKH     64
#define D_FF    4096
#define BATCH   4
#define SEQ     2048
#define NTOK    (BATCH * SEQ)   // 8192
#define LN_EPS  1e-5f
#define QKV_LD  3072
#define QSCALE  0.18033688011112042f   // 0.125 * log2(e)

typedef unsigned short u16;
typedef __attribute__((ext_vector_type(8))) short bf16x8;
typedef __attribute__((ext_vector_type(4))) float f32x4;

__device__ __forceinline__ u16 f2bf(float f) {
    union { float f; uint32_t u; } c; c.f = f;
    return (u16)((c.u + 0x7FFFu + ((c.u >> 16) & 1u)) >> 16);   // RNE
}
__device__ __forceinline__ float bf2f(u16 h) {
    union { uint32_t u; float f; } c; c.u = ((uint32_t)h) << 16;
    return c.f;
}

// async global->LDS, 16B/lane; lds base wave-uniform, HW writes base+lane*16
__device__ __forceinline__ void gload16(const u16* g, u16* lds) {
    __builtin_amdgcn_global_load_lds(
        (const __attribute__((address_space(1))) uint32_t*)g,
        (__attribute__((address_space(3))) uint32_t*)(uintptr_t)lds,
        16, 0, 0);
}

// ---------------------------------------------------------------------------
// bf16 GEMM: C[M,N] = A[M,K] @ Bt[N,K]^T + bias, MODE: 0 none, 1 relu, 2 qkv.
// 128x128 tile, BK=32, 4 waves, 4x4 16x16x32 MFMA frags/wave (m97 structure).
// MODE 2: bias selected among {bias,bias2,bias3} per 1024-col region; the
// first 1024 cols (Q) scaled by QSCALE (folds 1/sqrt(dk) and log2e for exp2).
// ---------------------------------------------------------------------------
__device__ __forceinline__ void store_out(float* p, float v) { *p = v; }
__device__ __forceinline__ void store_out(u16* p, float v)   { *p = f2bf(v); }

template <int MODE, typename OutT>
__global__ __launch_bounds__(256, 2) void gemm_bf16_kernel(
    const u16* __restrict__ A, const u16* __restrict__ Bt,
    const float* __restrict__ bias, const float* __restrict__ bias2,
    const float* __restrict__ bias3, OutT* __restrict__ C,
    int M, int N, int K)
{
    __shared__ u16 Alds[128 * 32];
    __shared__ u16 Blds[128 * 32];

    const int tid  = threadIdx.x;
    const int wave = tid >> 6;
    const int lane = tid & 63;
    const int lo   = lane & 15;
    const int hi   = lane >> 4;
    const int m0   = blockIdx.y << 7;
    const int n0   = blockIdx.x << 7;
    const int wr   = wave >> 1;
    const int wc   = wave & 1;

    const int srow = wave * 32 + (lane >> 2);
    const int scol = (lane & 3) * 8;
    const u16* Ag = A  + (size_t)(m0 + srow) * K + scol;
    const u16* Bg = Bt + (size_t)(n0 + srow) * K + scol;
    u16* AldsW = Alds + wave * 1024;
    u16* BldsW = Blds + wave * 1024;

    f32x4 acc[4][4];
#pragma unroll
    for (int i = 0; i < 4; ++i)
#pragma unroll
        for (int j = 0; j < 4; ++j)
#pragma unroll
            for (int r = 0; r < 4; ++r) acc[i][j][r] = 0.f;

    for (int k0 = 0; k0 < K; k0 += 32) {
        __syncthreads();
        gload16(Ag + k0,                  AldsW);
        gload16(Ag + k0 + 16 * (size_t)K, AldsW + 512);
        gload16(Bg + k0,                  BldsW);
        gload16(Bg + k0 + 16 * (size_t)K, BldsW + 512);
        __syncthreads();

        bf16x8 a[4], b[4];
#pragma unroll
        for (int i = 0; i < 4; ++i) {
            a[i] = *(const bf16x8*)&Alds[(wr * 64 + i * 16 + lo) * 32 + hi * 8];
            b[i] = *(const bf16x8*)&Blds[(wc * 64 + i * 16 + lo) * 32 + hi * 8];
        }
#pragma unroll
        for (int i = 0; i < 4; ++i)
#pragma unroll
            for (int j = 0; j < 4; ++j)
                acc[i][j] = __builtin_amdgcn_mfma_f32_16x16x32_bf16(
                                a[i], b[j], acc[i][j], 0, 0, 0);
    }

    const int crow = m0 + wr * 64 + hi * 4;
    const int ccol = n0 + wc * 64 + lo;
#pragma unroll
    for (int j = 0; j < 4; ++j) {
        const int col = ccol + j * 16;
        float bj;
        float sc = 1.0f;
        if (MODE == 2) {
            bj = (col < 1024) ? bias[col]
               : (col < 2048) ? bias2[col - 1024] : bias3[col - 2048];
            if (col < 1024) sc = QSCALE;
        } else {
            bj = bias[col];
        }
#pragma unroll
        for (int i = 0; i < 4; ++i)
#pragma unroll
            for (int r = 0; r < 4; ++r) {
                float v = acc[i][j][r] + bj;
                if (MODE == 1) v = fmaxf(v, 0.f);
                if (MODE == 2) v *= sc;
                store_out(&C[(size_t)(crow + i * 16 + r) * N + col], v);
            }
    }
}

// ---------------------------------------------------------------------------
// Flash attention, bf16 MFMA. Block = (b,h) x 128 q-rows; 4 waves x 32 rows.
// KV tile 64. K: linear LDS [64][64], XOR-swizzled content via pre-swizzled
// global_load_lds source. V: [dk][kv+pad] via 4x4 register transpose.
// Softmax in exp2 units (Q pre-scaled by QSCALE at the QKV GEMM).
// ---------------------------------------------------------------------------
__global__ __launch_bounds__(256, 2) void attn_mfma_kernel(
    const u16* __restrict__ QKV, u16* __restrict__ O)
{
    __shared__ u16 Klds[64 * 64];        // [kv][dk], chunk c holds global c^(kv&7)
    __shared__ u16 Vt[64 * 72];          // [dk][kv], pad 8
    __shared__ u16 Plds[4][32 * 72];     // per-wave P

    const int tid  = threadIdx.x;
    const int wave = tid >> 6;
    const int lane = tid & 63;
    const int lo   = lane & 15;
    const int hi   = lane >> 4;
    const int b    = blockIdx.x >> 4;
    const int h    = blockIdx.x & 15;
    const int q0   = blockIdx.y * 128 + wave * 32;
    const size_t rowb = (size_t)b * SEQ * QKV_LD + (size_t)h * DKH;
    const u16* Qg = QKV + rowb;
    const u16* Kg = QKV + rowb + 1024;
    const u16* Vg = QKV + rowb + 2048;

    // Q fragments (A-operand): row=lo, k = f*32 + hi*8 + e
    bf16x8 qf[2][2];
#pragma unroll
    for (int sub = 0; sub < 2; ++sub)
#pragma unroll
        for (int f = 0; f < 2; ++f)
            qf[sub][f] = *(const bf16x8*)
                &Qg[(size_t)(q0 + sub * 16 + lo) * QKV_LD + f * 32 + hi * 8];

    f32x4 oacc[2][4];
    float mrun[2][4], lrun[2][4];
#pragma unroll
    for (int sub = 0; sub < 2; ++sub) {
#pragma unroll
        for (int g = 0; g < 4; ++g)
#pragma unroll
            for (int r = 0; r < 4; ++r) oacc[sub][g][r] = 0.f;
#pragma unroll
        for (int r = 0; r < 4; ++r) { mrun[sub][r] = -1e30f; lrun[sub][r] = 0.f; }
    }

    // K staging: wave fills rows wave*16..+15 (2 gloads x 8 rows of 128B)
    const int krow = wave * 16 + (lane >> 3);
    const int ksrc = (((lane & 7) ^ (lane >> 3)) << 3);   // swizzled dk elem offset
    u16* kdst = Klds + wave * 1024;

    // V staging: thread owns 4kv x 4dk block
    const int vdk0 = (tid & 15) * 4;
    const int vkv  = (tid >> 4) * 4;

    for (int kv0 = 0; kv0 < SEQ; kv0 += 64) {
        __syncthreads();
        gload16(Kg + (size_t)(kv0 + krow) * QKV_LD + ksrc, kdst);
        gload16(Kg + (size_t)(kv0 + krow + 8) * QKV_LD + ksrc, kdst + 512);
        alignas(8) u16 e[4][4];
#pragma unroll
        for (int i = 0; i < 4; ++i)
            *(uint2*)e[i] = *(const uint2*)&Vg[(size_t)(kv0 + vkv + i) * QKV_LD + vdk0];
#pragma unroll
        for (int j = 0; j < 4; ++j) {
            alignas(8) u16 w[4] = { e[0][j], e[1][j], e[2][j], e[3][j] };
            *(uint2*)&Vt[(vdk0 + j) * 72 + vkv] = *(const uint2*)w;
        }
        __syncthreads();

        // S = Q K^T (exp2 units; scale already folded into Q)
        f32x4 s[2][4];
#pragma unroll
        for (int g = 0; g < 4; ++g)
#pragma unroll
            for (int r = 0; r < 4; ++r) { s[0][g][r] = 0.f; s[1][g][r] = 0.f; }
#pragma unroll
        for (int g = 0; g < 4; ++g)
#pragma unroll
            for (int f = 0; f < 2; ++f) {
                const bf16x8 kf = *(const bf16x8*)
                    &Klds[(g * 16 + lo) * 64 + (((f * 4 + hi) ^ (lo & 7)) << 3)];
                s[0][g] = __builtin_amdgcn_mfma_f32_16x16x32_bf16(qf[0][f], kf, s[0][g], 0, 0, 0);
                s[1][g] = __builtin_amdgcn_mfma_f32_16x16x32_bf16(qf[1][f], kf, s[1][g], 0, 0, 0);
            }

        // online softmax per 16-row sub-block, defer-max (THR=8 in exp2 units)
#pragma unroll
        for (int sub = 0; sub < 2; ++sub) {
            float tmax[4];
            int need = 0;
#pragma unroll
            for (int r = 0; r < 4; ++r) {
                float tm = fmaxf(fmaxf(s[sub][0][r], s[sub][1][r]),
                                 fmaxf(s[sub][2][r], s[sub][3][r]));
#pragma unroll
                for (int m = 1; m < 16; m <<= 1) tm = fmaxf(tm, __shfl_xor(tm, m, 64));
                tmax[r] = tm;
                need |= (tm > mrun[sub][r] + 8.0f) ? 1 : 0;
            }
            if (__any(need)) {
#pragma unroll
                for (int r = 0; r < 4; ++r) {
                    const float mnew = fmaxf(mrun[sub][r], tmax[r]);
                    const float corr = exp2f(mrun[sub][r] - mnew);
                    mrun[sub][r] = mnew;
                    lrun[sub][r] *= corr;
#pragma unroll
                    for (int g = 0; g < 4; ++g) oacc[sub][g][r] *= corr;
                }
            }
            u16* Pw = Plds[wave] + sub * 16 * 72;
#pragma unroll
            for (int r = 0; r < 4; ++r) {
                const float p0 = exp2f(s[sub][0][r] - mrun[sub][r]);
                const float p1 = exp2f(s[sub][1][r] - mrun[sub][r]);
                const float p2 = exp2f(s[sub][2][r] - mrun[sub][r]);
                const float p3 = exp2f(s[sub][3][r] - mrun[sub][r]);
                float ls = (p0 + p1) + (p2 + p3);
#pragma unroll
                for (int m = 1; m < 16; m <<= 1) ls += __shfl_xor(ls, m, 64);
                lrun[sub][r] += ls;
                uint32_t pk01, pk23;
                asm("v_cvt_pk_bf16_f32 %0, %1, %2" : "=v"(pk01) : "v"(p0), "v"(p1));
                asm("v_cvt_pk_bf16_f32 %0, %1, %2" : "=v"(pk23) : "v"(p2), "v"(p3));
                const int pr = (hi * 4 + r) * 72 + lo;
                Pw[pr]      = (u16)pk01;
                Pw[pr + 16] = (u16)(pk01 >> 16);
                Pw[pr + 32] = (u16)pk23;
                Pw[pr + 48] = (u16)(pk23 >> 16);
            }
        }

        asm volatile("s_waitcnt lgkmcnt(0)" ::: "memory");
        __builtin_amdgcn_sched_barrier(0);

        // O += P V ; V frags shared across both sub-blocks
        bf16x8 pf[2][2];
#pragma unroll
        for (int sub = 0; sub < 2; ++sub)
#pragma unroll
            for (int f = 0; f < 2; ++f)
                pf[sub][f] = *(const bf16x8*)
                    &Plds[wave][(sub * 16 + lo) * 72 + f * 32 + hi * 8];
#pragma unroll
        for (int g = 0; g < 4; ++g)
#pragma unroll
            for (int f = 0; f < 2; ++f) {
                const bf16x8 vf = *(const bf16x8*)&Vt[(g * 16 + lo) * 72 + f * 32 + hi * 8];
                oacc[0][g] = __builtin_amdgcn_mfma_f32_16x16x32_bf16(pf[0][f], vf, oacc[0][g], 0, 0, 0);
                oacc[1][g] = __builtin_amdgcn_mfma_f32_16x16x32_bf16(pf[1][f], vf, oacc[1][g], 0, 0, 0);
            }
    }

    const size_t obase = (size_t)b * SEQ * D_MODEL + (size_t)h * DKH;
#pragma unroll
    for (int sub = 0; sub < 2; ++sub)
#pragma unroll
        for (int r = 0; r < 4; ++r) {
            const float inv = 1.0f / lrun[sub][r];
            const size_t ro = obase + (size_t)(q0 + sub * 16 + hi * 4 + r) * D_MODEL;
#pragma unroll
            for (int g = 0; g < 4; ++g)
                O[ro + g * 16 + lo] = f2bf(oacc[sub][g][r] * inv);
        }
}

// ---------------------------------------------------------------------------
// W[K][N] f32 -> Wt[N][K] bf16 (tiled 32x32 transpose)
// ---------------------------------------------------------------------------
__global__ __launch_bounds__(256) void transpose_w_kernel(
    const float* __restrict__ W, u16* __restrict__ Wt, int K, int N)
{
    __shared__ float t[32][33];
    const int n0 = blockIdx.x << 5;
    const int k0 = blockIdx.y << 5;
    const int tx = threadIdx.x & 31;
    const int ty = threadIdx.x >> 5;
#pragma unroll
    for (int i = 0; i < 4; ++i)
        t[ty + i * 8][tx] = W[(size_t)(k0 + ty + i * 8) * N + n0 + tx];
    __syncthreads();
#pragma unroll
    for (int i = 0; i < 4; ++i)
        Wt[(size_t)(n0 + ty + i * 8) * K + k0 + tx] = f2bf(t[tx][ty + i * 8]);
}

// f32 -> bf16 bulk convert, 8 elems/thread
__global__ __launch_bounds__(256) void cvt_kernel(
    const float* __restrict__ src, u16* __restrict__ dst)
{
    const size_t i = ((size_t)blockIdx.x * 256 + threadIdx.x) * 8;
    const float4 a = *(const float4*)&src[i];
    const float4 b = *(const float4*)&src[i + 4];
    alignas(16) u16 e[8] = { f2bf(a.x), f2bf(a.y), f2bf(a.z), f2bf(a.w),
                             f2bf(b.x), f2bf(b.y), f2bf(b.z), f2bf(b.w) };
    *(int4*)&dst[i] = *(const int4*)e;
}

// ---------------------------------------------------------------------------
// out = LayerNorm(X + Y)*gamma + beta; mixed dtypes. One block per row.
// Safe with Out aliasing X or Y (each thread reads before it writes).
// ---------------------------------------------------------------------------
__device__ __forceinline__ float4 ld4(const float* p) { return *(const float4*)p; }
__device__ __forceinline__ float4 ld4(const u16* p) {
    alignas(8) u16 e[4];
    *(uint2*)e = *(const uint2*)p;
    return make_float4(bf2f(e[0]), bf2f(e[1]), bf2f(e[2]), bf2f(e[3]));
}
__device__ __forceinline__ void st4(float* p, float4 v) { *(float4*)p = v; }
__device__ __forceinline__ void st4(u16* p, float4 v) {
    alignas(8) u16 e[4] = { f2bf(v.x), f2bf(v.y), f2bf(v.z), f2bf(v.w) };
    *(uint2*)p = *(const uint2*)e;
}

template <typename XT, typename YT, typename OT>
__global__ __launch_bounds__(256) void add_ln_kernel(
    const XT* __restrict__ X, const YT* __restrict__ Y,
    const float* __restrict__ gamma, const float* __restrict__ beta,
    OT* __restrict__ Out)
{
    const int row = blockIdx.x;
    const int i0  = threadIdx.x << 2;
    const float4 xv = ld4(X + (size_t)row * D_MODEL + i0);
    const float4 yv = ld4(Y + (size_t)row * D_MODEL + i0);
    const float4 v  = make_float4(xv.x + yv.x, xv.y + yv.y, xv.z + yv.z, xv.w + yv.w);

    float s1 = v.x + v.y + v.z + v.w;
    float s2 = v.x * v.x + v.y * v.y + v.z * v.z + v.w * v.w;
#pragma unroll
    for (int off = 32; off > 0; off >>= 1) {
        s1 += __shfl_xor(s1, off, 64);
        s2 += __shfl_xor(s2, off, 64);
    }
    __shared__ float red[8];
    const int wid = threadIdx.x >> 6;
    if ((threadIdx.x & 63) == 0) { red[wid] = s1; red[wid + 4] = s2; }
    __syncthreads();
    s1 = red[0] + red[1] + red[2] + red[3];
    s2 = red[4] + red[5] + red[6] + red[7];

    const float mu   = s1 * (1.0f / D_MODEL);
    const float var  = s2 * (1.0f / D_MODEL) - mu * mu;
    const float rstd = rsqrtf(var + LN_EPS);

    const float4 g  = *(const float4*)(gamma + i0);
    const float4 bb = *(const float4*)(beta + i0);
    float4 ov;
    ov.x = (v.x - mu) * rstd * g.x + bb.x;
    ov.y = (v.y - mu) * rstd * g.y + bb.y;
    ov.z = (v.z - mu) * rstd * g.z + bb.z;
    ov.w = (v.w - mu) * rstd * g.w + bb.w;
    st4(Out + (size_t)row * D_MODEL + i0, ov);
}

// ---------------------------------------------------------------------------
extern "C" void kernel_launch(void* const* d_in, const int* in_sizes, int n_in,
                              void* d_out, int out_size, void* d_ws, size_t ws_size,
                              hipStream_t stream)
{
    const float* x     = (const float*)d_in[0];
    const float* Wq    = (const float*)d_in[1];
    const float* bq    = (const float*)d_in[2];
    const float* Wk    = (const float*)d_in[3];
    const float* bk    = (const float*)d_in[4];
    const float* Wv    = (const float*)d_in[5];
    const float* bv    = (const float*)d_in[6];
    const float* Wo    = (const float*)d_in[7];
    const float* bo    = (const float*)d_in[8];
    const float* W1    = (const float*)d_in[9];
    const float* b1    = (const float*)d_in[10];
    const float* W2    = (const float*)d_in[11];
    const float* b2    = (const float*)d_in[12];
    const float* g1    = (const float*)d_in[13];
    const float* beta1 = (const float*)d_in[14];
    const float* g2    = (const float*)d_in[15];
    const float* beta2 = (const float*)d_in[16];
    float* out = (float*)d_out;

    // workspace (u16 units) — 62914560 u16 = 120 MB (same as round 1)
    const size_t TOKD = (size_t)NTOK * D_MODEL;
    u16* xb    = (u16*)d_ws;
    u16* wqkvT = xb + TOKD;                              // [3072][1024]
    u16* woT   = wqkvT + (size_t)3 * D_MODEL * D_MODEL;
    u16* w1T   = woT + (size_t)D_MODEL * D_MODEL;        // [4096][1024]
    u16* w2T   = w1T + (size_t)D_MODEL * D_FF;           // [1024][4096]
    u16* qkv   = w2T + (size_t)D_FF * D_MODEL;           // [NTOK][3072]
    u16* ctx   = qkv + (size_t)NTOK * QKV_LD;
    u16* y1    = ctx + TOKD;
    u16* x2    = y1;                                     // LN1 in place
    u16* h1    = qkv;                                    // spans qkv+ctx = NTOK*D_FF

    const dim3 blk(256);

    cvt_kernel<<<dim3(TOKD / 2048), blk, 0, stream>>>(x, xb);
    transpose_w_kernel<<<dim3(D_MODEL / 32, D_MODEL / 32), blk, 0, stream>>>(Wq, wqkvT, D_MODEL, D_MODEL);
    transpose_w_kernel<<<dim3(D_MODEL / 32, D_MODEL / 32), blk, 0, stream>>>(Wk, wqkvT + (size_t)D_MODEL * D_MODEL, D_MODEL, D_MODEL);
    transpose_w_kernel<<<dim3(D_MODEL / 32, D_MODEL / 32), blk, 0, stream>>>(Wv, wqkvT + (size_t)2 * D_MODEL * D_MODEL, D_MODEL, D_MODEL);
    transpose_w_kernel<<<dim3(D_MODEL / 32, D_MODEL / 32), blk, 0, stream>>>(Wo, woT, D_MODEL, D_MODEL);
    transpose_w_kernel<<<dim3(D_FF / 32,    D_MODEL / 32), blk, 0, stream>>>(W1, w1T, D_MODEL, D_FF);
    transpose_w_kernel<<<dim3(D_MODEL / 32, D_FF / 32),    blk, 0, stream>>>(W2, w2T, D_FF, D_MODEL);

    // fused QKV projection (Q pre-scaled for exp2 softmax)
    gemm_bf16_kernel<2, u16><<<dim3(QKV_LD / 128, NTOK / 128), blk, 0, stream>>>(
        xb, wqkvT, bq, bk, bv, qkv, NTOK, QKV_LD, D_MODEL);

    attn_mfma_kernel<<<dim3(BATCH * N_HEADS, SEQ / 128), blk, 0, stream>>>(qkv, ctx);

    gemm_bf16_kernel<0, u16><<<dim3(D_MODEL / 128, NTOK / 128), blk, 0, stream>>>(
        ctx, woT, bo, bo, bo, y1, NTOK, D_MODEL, D_MODEL);

    add_ln_kernel<float, u16, u16><<<dim3(NTOK), blk, 0, stream>>>(x, y1, g1, beta1, x2);

    gemm_bf16_kernel<1, u16><<<dim3(D_FF / 128, NTOK / 128), blk, 0, stream>>>(
        x2, w1T, b1, b1, b1, h1, NTOK, D_FF, D_MODEL);
    gemm_bf16_kernel<0, float><<<dim3(D_MODEL / 128, NTOK / 128), blk, 0, stream>>>(
        h1, w2T, b2, b2, b2, out, NTOK, D_MODEL, D_FF);

    add_ln_kernel<u16, float, float><<<dim3(NTOK), blk, 0, stream>>>(x2, out, g2, beta2, out);

    (void)in_sizes; (void)n_in; (void)out_size; (void)ws_size;
}

// Round 4
// 450.822 us; speedup vs baseline: 10.8260x; 1.2219x over previous
//
#include <hip/hip_runtime.h>
#include <math.h>
#include <stdint.h>

// EncoderLayer on MI355X — Round 3: swapped-QK^T attention (m214 structure).
// S^T = mfma_32x32x16(K, Q): per-lane softmax (31 fmax + 1 shfl), P stays in
// registers (cvt_pk + word-shfl redistribution), K/V^T in XOR-swizzled LDS.
// GEMMs unchanged (m97 structure, fused QKV with Q pre-scale).

#define D_MODEL 1024
#define N_HEADS 16
#define DKH     64
#define D_FF    4096
#define BATCH   4
#define SEQ     2048
#define NTOK    (BATCH * SEQ)   // 8192
#define LN_EPS  1e-5f
#define QKV_LD  3072
#define QSCALE  0.18033688011112042f   // 0.125 * log2(e)

typedef unsigned short u16;
typedef __attribute__((ext_vector_type(8))) short bf16x8;
typedef __attribute__((ext_vector_type(4))) float f32x4;
typedef __attribute__((ext_vector_type(16))) float f32x16;

__device__ __forceinline__ u16 f2bf(float f) {
    union { float f; uint32_t u; } c; c.f = f;
    return (u16)((c.u + 0x7FFFu + ((c.u >> 16) & 1u)) >> 16);   // RNE
}
__device__ __forceinline__ float bf2f(u16 h) {
    union { uint32_t u; float f; } c; c.u = ((uint32_t)h) << 16;
    return c.f;
}

// async global->LDS, 16B/lane; lds base wave-uniform, HW writes base+lane*16
__device__ __forceinline__ void gload16(const u16* g, u16* lds) {
    __builtin_amdgcn_global_load_lds(
        (const __attribute__((address_space(1))) uint32_t*)g,
        (__attribute__((address_space(3))) uint32_t*)(uintptr_t)lds,
        16, 0, 0);
}

// ---------------------------------------------------------------------------
// bf16 GEMM: C[M,N] = A[M,K] @ Bt[N,K]^T + bias, MODE: 0 none, 1 relu, 2 qkv.
// 128x128 tile, BK=32, 4 waves, 4x4 16x16x32 MFMA frags/wave (m97 structure).
// ---------------------------------------------------------------------------
__device__ __forceinline__ void store_out(float* p, float v) { *p = v; }
__device__ __forceinline__ void store_out(u16* p, float v)   { *p = f2bf(v); }

template <int MODE, typename OutT>
__global__ __launch_bounds__(256, 2) void gemm_bf16_kernel(
    const u16* __restrict__ A, const u16* __restrict__ Bt,
    const float* __restrict__ bias, const float* __restrict__ bias2,
    const float* __restrict__ bias3, OutT* __restrict__ C,
    int M, int N, int K)
{
    __shared__ u16 Alds[128 * 32];
    __shared__ u16 Blds[128 * 32];

    const int tid  = threadIdx.x;
    const int wave = tid >> 6;
    const int lane = tid & 63;
    const int lo   = lane & 15;
    const int hi   = lane >> 4;
    const int m0   = blockIdx.y << 7;
    const int n0   = blockIdx.x << 7;
    const int wr   = wave >> 1;
    const int wc   = wave & 1;

    const int srow = wave * 32 + (lane >> 2);
    const int scol = (lane & 3) * 8;
    const u16* Ag = A  + (size_t)(m0 + srow) * K + scol;
    const u16* Bg = Bt + (size_t)(n0 + srow) * K + scol;
    u16* AldsW = Alds + wave * 1024;
    u16* BldsW = Blds + wave * 1024;

    f32x4 acc[4][4];
#pragma unroll
    for (int i = 0; i < 4; ++i)
#pragma unroll
        for (int j = 0; j < 4; ++j)
#pragma unroll
            for (int r = 0; r < 4; ++r) acc[i][j][r] = 0.f;

    for (int k0 = 0; k0 < K; k0 += 32) {
        __syncthreads();
        gload16(Ag + k0,                  AldsW);
        gload16(Ag + k0 + 16 * (size_t)K, AldsW + 512);
        gload16(Bg + k0,                  BldsW);
        gload16(Bg + k0 + 16 * (size_t)K, BldsW + 512);
        __syncthreads();

        bf16x8 a[4], b[4];
#pragma unroll
        for (int i = 0; i < 4; ++i) {
            a[i] = *(const bf16x8*)&Alds[(wr * 64 + i * 16 + lo) * 32 + hi * 8];
            b[i] = *(const bf16x8*)&Blds[(wc * 64 + i * 16 + lo) * 32 + hi * 8];
        }
#pragma unroll
        for (int i = 0; i < 4; ++i)
#pragma unroll
            for (int j = 0; j < 4; ++j)
                acc[i][j] = __builtin_amdgcn_mfma_f32_16x16x32_bf16(
                                a[i], b[j], acc[i][j], 0, 0, 0);
    }

    const int crow = m0 + wr * 64 + hi * 4;
    const int ccol = n0 + wc * 64 + lo;
#pragma unroll
    for (int j = 0; j < 4; ++j) {
        const int col = ccol + j * 16;
        float bj;
        float sc = 1.0f;
        if (MODE == 2) {
            bj = (col < 1024) ? bias[col]
               : (col < 2048) ? bias2[col - 1024] : bias3[col - 2048];
            if (col < 1024) sc = QSCALE;
        } else {
            bj = bias[col];
        }
#pragma unroll
        for (int i = 0; i < 4; ++i)
#pragma unroll
            for (int r = 0; r < 4; ++r) {
                float v = acc[i][j][r] + bj;
                if (MODE == 1) v = fmaxf(v, 0.f);
                if (MODE == 2) v *= sc;
                store_out(&C[(size_t)(crow + i * 16 + r) * N + col], v);
            }
    }
}

// ---------------------------------------------------------------------------
// Flash attention, swapped QK^T on 32x32x16 MFMA.
// Block = (b,h) x 128 q-rows, 4 waves x 32 q-rows. KV tile 64.
// S^T = mfma(K, Q): lane pair (l, l+32) owns q-row l&31; 32 scores lane-local.
// K and V^T in LDS, 16B-chunk XOR-swizzled (chunk c at c^(row&7)).
// P built in-register: cvt_pk -> 4 word-shfl + select per fragment.
// ---------------------------------------------------------------------------
__global__ __launch_bounds__(256, 3) void attn_mfma_kernel(
    const u16* __restrict__ QKV, u16* __restrict__ O)
{
    __shared__ u16 Klds[64 * 64];   // [kv][dk]
    __shared__ u16 Vlds[64 * 64];   // [dk][kv] (transposed)

    const int tid  = threadIdx.x;
    const int wave = tid >> 6;
    const int lane = tid & 63;
    const int l31  = lane & 31;
    const int hi5  = lane >> 5;
    const int b    = blockIdx.x >> 4;
    const int h    = blockIdx.x & 15;
    const int q0   = blockIdx.y * 128 + wave * 32;
    const size_t rowb = (size_t)b * SEQ * QKV_LD + (size_t)h * DKH;
    const u16* Qg = QKV + rowb;
    const u16* Kg = QKV + rowb + 1024;
    const u16* Vg = QKV + rowb + 2048;

    // Q as B-operand: col(q) = l31, k = 16f + 8*hi5 + e  (held for whole kernel)
    bf16x8 qf[4];
#pragma unroll
    for (int f = 0; f < 4; ++f)
        qf[f] = *(const bf16x8*)&Qg[(size_t)(q0 + l31) * QKV_LD + 16 * f + 8 * hi5];

    // O^T accumulator: D[d][q], q = l31, d = 32g + (r&3) + 8*(r>>2) + 4*hi5
    f32x16 oacc[2];
#pragma unroll
    for (int g = 0; g < 2; ++g)
#pragma unroll
        for (int r = 0; r < 16; ++r) oacc[g][r] = 0.f;
    float mrun = -1e30f, lrun = 0.f;   // per-lane; q-row stats (pair-consistent)

    // K staging: lane l of wave w -> LDS row w*8+(l>>3), chunk position l&7;
    // source chunk pre-swizzled so position c holds global chunk c^(row&7)
    const int krow = wave * 8 + (lane >> 3);
    const int kchk = ((lane & 7) ^ ((lane >> 3) & 7)) << 3;
    u16* kdst = Klds + wave * 512;

    // V transpose staging: thread owns 4 kv x 4 dk
    const int vdk0 = (tid & 15) * 4;
    const int vkv  = (tid >> 4) * 4;
    const int vchk = vkv >> 3;
    const int vsub = vkv & 7;

    for (int kv0 = 0; kv0 < SEQ; kv0 += 64) {
        __syncthreads();
        gload16(Kg + (size_t)(kv0 + krow) * QKV_LD + kchk,      kdst);
        gload16(Kg + (size_t)(kv0 + krow + 32) * QKV_LD + kchk, kdst + 32 * 64);
        alignas(8) u16 e[4][4];
#pragma unroll
        for (int i = 0; i < 4; ++i)
            *(uint2*)e[i] = *(const uint2*)&Vg[(size_t)(kv0 + vkv + i) * QKV_LD + vdk0];
#pragma unroll
        for (int j = 0; j < 4; ++j) {
            alignas(8) u16 w4[4] = { e[0][j], e[1][j], e[2][j], e[3][j] };
            const int row = vdk0 + j;
            *(uint2*)&Vlds[row * 64 + ((vchk ^ (row & 7)) << 3) + vsub] = *(const uint2*)w4;
        }
        __syncthreads();

        // S^T = K·Q for the two 32-kv halves (exp2 units, scale folded into Q)
        f32x16 s0, s1;
#pragma unroll
        for (int r = 0; r < 16; ++r) { s0[r] = 0.f; s1[r] = 0.f; }
#pragma unroll
        for (int f = 0; f < 4; ++f) {
            const int rc = ((2 * f + hi5) ^ (l31 & 7)) << 3;
            const bf16x8 ka = *(const bf16x8*)&Klds[l31 * 64 + rc];
            const bf16x8 kb = *(const bf16x8*)&Klds[(32 + l31) * 64 + rc];
            s0 = __builtin_amdgcn_mfma_f32_32x32x16_bf16(ka, qf[f], s0, 0, 0, 0);
            s1 = __builtin_amdgcn_mfma_f32_32x32x16_bf16(kb, qf[f], s1, 0, 0, 0);
        }

        // per-lane online softmax; one cross-lane exchange for the pair max
        float tm = s0[0];
#pragma unroll
        for (int r = 1; r < 16; ++r) tm = fmaxf(tm, s0[r]);
#pragma unroll
        for (int r = 0; r < 16; ++r) tm = fmaxf(tm, s1[r]);
        tm = fmaxf(tm, __shfl_xor(tm, 32, 64));
        if (__any(tm > mrun + 8.0f)) {              // defer-max (T13)
            const float mnew = fmaxf(mrun, tm);
            const float corr = exp2f(mrun - mnew);
            lrun *= corr;
#pragma unroll
            for (int g = 0; g < 2; ++g)
#pragma unroll
                for (int r = 0; r < 16; ++r) oacc[g][r] *= corr;
            mrun = mnew;
        }
        float ls = 0.f;
#pragma unroll
        for (int r = 0; r < 16; ++r) { s0[r] = exp2f(s0[r] - mrun); ls += s0[r]; }
#pragma unroll
        for (int r = 0; r < 16; ++r) { s1[r] = exp2f(s1[r] - mrun); ls += s1[r]; }
        lrun += ls;   // per-lane partial; pair-combined in epilogue

        // P B-frags: place P[kv][q] per layout k = 16f + 8*hi5 + e (matches V read)
        auto mkfrag = [&](float a0, float a1, float a2, float a3,
                          float a4, float a5, float a6, float a7) -> bf16x8 {
            uint32_t A, B, C, D;
            asm("v_cvt_pk_bf16_f32 %0, %1, %2" : "=v"(A) : "v"(a0), "v"(a1));
            asm("v_cvt_pk_bf16_f32 %0, %1, %2" : "=v"(B) : "v"(a2), "v"(a3));
            asm("v_cvt_pk_bf16_f32 %0, %1, %2" : "=v"(C) : "v"(a4), "v"(a5));
            asm("v_cvt_pk_bf16_f32 %0, %1, %2" : "=v"(D) : "v"(a6), "v"(a7));
            const uint32_t Ax = (uint32_t)__shfl_xor((int)A, 32, 64);
            const uint32_t Bx = (uint32_t)__shfl_xor((int)B, 32, 64);
            const uint32_t Cx = (uint32_t)__shfl_xor((int)C, 32, 64);
            const uint32_t Dx = (uint32_t)__shfl_xor((int)D, 32, 64);
            union { uint32_t w[4]; bf16x8 v; } u;
            u.w[0] = hi5 ? Cx : A;   // lo: kv+0,1   hi: kv+8,9
            u.w[1] = hi5 ? Dx : B;   // lo: kv+2,3   hi: kv+10,11
            u.w[2] = hi5 ? C  : Ax;  // lo: kv+4,5   hi: kv+12,13
            u.w[3] = hi5 ? D  : Bx;  // lo: kv+6,7   hi: kv+14,15
            return u.v;
        };
        bf16x8 pb0 = mkfrag(s0[0], s0[1], s0[2],  s0[3],  s0[4],  s0[5],  s0[6],  s0[7]);
        bf16x8 pb1 = mkfrag(s0[8], s0[9], s0[10], s0[11], s0[12], s0[13], s0[14], s0[15]);
        bf16x8 pb2 = mkfrag(s1[0], s1[1], s1[2],  s1[3],  s1[4],  s1[5],  s1[6],  s1[7]);
        bf16x8 pb3 = mkfrag(s1[8], s1[9], s1[10], s1[11], s1[12], s1[13], s1[14], s1[15]);

        // O^T += V^T · P
#pragma unroll
        for (int f = 0; f < 4; ++f) {
            const bf16x8 pf = (f == 0) ? pb0 : (f == 1) ? pb1 : (f == 2) ? pb2 : pb3;
            const int rc = ((2 * f + hi5) ^ (l31 & 7)) << 3;
            const bf16x8 va = *(const bf16x8*)&Vlds[l31 * 64 + rc];
            const bf16x8 vb = *(const bf16x8*)&Vlds[(32 + l31) * 64 + rc];
            oacc[0] = __builtin_amdgcn_mfma_f32_32x32x16_bf16(va, pf, oacc[0], 0, 0, 0);
            oacc[1] = __builtin_amdgcn_mfma_f32_32x32x16_bf16(vb, pf, oacc[1], 0, 0, 0);
        }
    }

    lrun += __shfl_xor(lrun, 32, 64);
    const float inv = 1.0f / lrun;
    u16* Orow = O + (size_t)b * SEQ * D_MODEL + (size_t)(q0 + l31) * D_MODEL + h * DKH;
#pragma unroll
    for (int g = 0; g < 2; ++g)
#pragma unroll
        for (int rp = 0; rp < 8; ++rp) {
            const int r = rp * 2;
            const float v0 = oacc[g][r] * inv;
            const float v1 = oacc[g][r + 1] * inv;
            uint32_t pk;
            asm("v_cvt_pk_bf16_f32 %0, %1, %2" : "=v"(pk) : "v"(v0), "v"(v1));
            const int d = 32 * g + (r & 3) + 8 * (r >> 2) + 4 * hi5;
            *(uint32_t*)&Orow[d] = pk;
        }
}

// ---------------------------------------------------------------------------
// W[K][N] f32 -> Wt[N][K] bf16 (tiled 32x32 transpose)
// ---------------------------------------------------------------------------
__global__ __launch_bounds__(256) void transpose_w_kernel(
    const float* __restrict__ W, u16* __restrict__ Wt, int K, int N)
{
    __shared__ float t[32][33];
    const int n0 = blockIdx.x << 5;
    const int k0 = blockIdx.y << 5;
    const int tx = threadIdx.x & 31;
    const int ty = threadIdx.x >> 5;
#pragma unroll
    for (int i = 0; i < 4; ++i)
        t[ty + i * 8][tx] = W[(size_t)(k0 + ty + i * 8) * N + n0 + tx];
    __syncthreads();
#pragma unroll
    for (int i = 0; i < 4; ++i)
        Wt[(size_t)(n0 + ty + i * 8) * K + k0 + tx] = f2bf(t[tx][ty + i * 8]);
}

// f32 -> bf16 bulk convert, 8 elems/thread
__global__ __launch_bounds__(256) void cvt_kernel(
    const float* __restrict__ src, u16* __restrict__ dst)
{
    const size_t i = ((size_t)blockIdx.x * 256 + threadIdx.x) * 8;
    const float4 a = *(const float4*)&src[i];
    const float4 b = *(const float4*)&src[i + 4];
    alignas(16) u16 e[8] = { f2bf(a.x), f2bf(a.y), f2bf(a.z), f2bf(a.w),
                             f2bf(b.x), f2bf(b.y), f2bf(b.z), f2bf(b.w) };
    *(int4*)&dst[i] = *(const int4*)e;
}

// ---------------------------------------------------------------------------
// out = LayerNorm(X + Y)*gamma + beta; mixed dtypes. One block per row.
// ---------------------------------------------------------------------------
__device__ __forceinline__ float4 ld4(const float* p) { return *(const float4*)p; }
__device__ __forceinline__ float4 ld4(const u16* p) {
    alignas(8) u16 e[4];
    *(uint2*)e = *(const uint2*)p;
    return make_float4(bf2f(e[0]), bf2f(e[1]), bf2f(e[2]), bf2f(e[3]));
}
__device__ __forceinline__ void st4(float* p, float4 v) { *(float4*)p = v; }
__device__ __forceinline__ void st4(u16* p, float4 v) {
    alignas(8) u16 e[4] = { f2bf(v.x), f2bf(v.y), f2bf(v.z), f2bf(v.w) };
    *(uint2*)p = *(const uint2*)e;
}

template <typename XT, typename YT, typename OT>
__global__ __launch_bounds__(256) void add_ln_kernel(
    const XT* __restrict__ X, const YT* __restrict__ Y,
    const float* __restrict__ gamma, const float* __restrict__ beta,
    OT* __restrict__ Out)
{
    const int row = blockIdx.x;
    const int i0  = threadIdx.x << 2;
    const float4 xv = ld4(X + (size_t)row * D_MODEL + i0);
    const float4 yv = ld4(Y + (size_t)row * D_MODEL + i0);
    const float4 v  = make_float4(xv.x + yv.x, xv.y + yv.y, xv.z + yv.z, xv.w + yv.w);

    float s1 = v.x + v.y + v.z + v.w;
    float s2 = v.x * v.x + v.y * v.y + v.z * v.z + v.w * v.w;
#pragma unroll
    for (int off = 32; off > 0; off >>= 1) {
        s1 += __shfl_xor(s1, off, 64);
        s2 += __shfl_xor(s2, off, 64);
    }
    __shared__ float red[8];
    const int wid = threadIdx.x >> 6;
    if ((threadIdx.x & 63) == 0) { red[wid] = s1; red[wid + 4] = s2; }
    __syncthreads();
    s1 = red[0] + red[1] + red[2] + red[3];
    s2 = red[4] + red[5] + red[6] + red[7];

    const float mu   = s1 * (1.0f / D_MODEL);
    const float var  = s2 * (1.0f / D_MODEL) - mu * mu;
    const float rstd = rsqrtf(var + LN_EPS);

    const float4 g  = *(const float4*)(gamma + i0);
    const float4 bb = *(const float4*)(beta + i0);
    float4 ov;
    ov.x = (v.x - mu) * rstd * g.x + bb.x;
    ov.y = (v.y - mu) * rstd * g.y + bb.y;
    ov.z = (v.z - mu) * rstd * g.z + bb.z;
    ov.w = (v.w - mu) * rstd * g.w + bb.w;
    st4(Out + (size_t)row * D_MODEL + i0, ov);
}

// ---------------------------------------------------------------------------
extern "C" void kernel_launch(void* const* d_in, const int* in_sizes, int n_in,
                              void* d_out, int out_size, void* d_ws, size_t ws_size,
                              hipStream_t stream)
{
    const float* x     = (const float*)d_in[0];
    const float* Wq    = (const float*)d_in[1];
    const float* bq    = (const float*)d_in[2];
    const float* Wk    = (const float*)d_in[3];
    const float* bk    = (const float*)d_in[4];
    const float* Wv    = (const float*)d_in[5];
    const float* bv    = (const float*)d_in[6];
    const float* Wo    = (const float*)d_in[7];
    const float* bo    = (const float*)d_in[8];
    const float* W1    = (const float*)d_in[9];
    const float* b1    = (const float*)d_in[10];
    const float* W2    = (const float*)d_in[11];
    const float* b2    = (const float*)d_in[12];
    const float* g1    = (const float*)d_in[13];
    const float* beta1 = (const float*)d_in[14];
    const float* g2    = (const float*)d_in[15];
    const float* beta2 = (const float*)d_in[16];
    float* out = (float*)d_out;

    const size_t TOKD = (size_t)NTOK * D_MODEL;
    u16* xb    = (u16*)d_ws;
    u16* wqkvT = xb + TOKD;                              // [3072][1024]
    u16* woT   = wqkvT + (size_t)3 * D_MODEL * D_MODEL;
    u16* w1T   = woT + (size_t)D_MODEL * D_MODEL;        // [4096][1024]
    u16* w2T   = w1T + (size_t)D_MODEL * D_FF;           // [1024][4096]
    u16* qkv   = w2T + (size_t)D_FF * D_MODEL;           // [NTOK][3072]
    u16* ctx   = qkv + (size_t)NTOK * QKV_LD;
    u16* y1    = ctx + TOKD;
    u16* x2    = y1;                                     // LN1 in place
    u16* h1    = qkv;                                    // spans qkv+ctx

    const dim3 blk(256);

    cvt_kernel<<<dim3(TOKD / 2048), blk, 0, stream>>>(x, xb);
    transpose_w_kernel<<<dim3(D_MODEL / 32, D_MODEL / 32), blk, 0, stream>>>(Wq, wqkvT, D_MODEL, D_MODEL);
    transpose_w_kernel<<<dim3(D_MODEL / 32, D_MODEL / 32), blk, 0, stream>>>(Wk, wqkvT + (size_t)D_MODEL * D_MODEL, D_MODEL, D_MODEL);
    transpose_w_kernel<<<dim3(D_MODEL / 32, D_MODEL / 32), blk, 0, stream>>>(Wv, wqkvT + (size_t)2 * D_MODEL * D_MODEL, D_MODEL, D_MODEL);
    transpose_w_kernel<<<dim3(D_MODEL / 32, D_MODEL / 32), blk, 0, stream>>>(Wo, woT, D_MODEL, D_MODEL);
    transpose_w_kernel<<<dim3(D_FF / 32,    D_MODEL / 32), blk, 0, stream>>>(W1, w1T, D_MODEL, D_FF);
    transpose_w_kernel<<<dim3(D_MODEL / 32, D_FF / 32),    blk, 0, stream>>>(W2, w2T, D_FF, D_MODEL);

    // fused QKV projection (Q pre-scaled for exp2 softmax)
    gemm_bf16_kernel<2, u16><<<dim3(QKV_LD / 128, NTOK / 128), blk, 0, stream>>>(
        xb, wqkvT, bq, bk, bv, qkv, NTOK, QKV_LD, D_MODEL);

    attn_mfma_kernel<<<dim3(BATCH * N_HEADS, SEQ / 128), blk, 0, stream>>>(qkv, ctx);

    gemm_bf16_kernel<0, u16><<<dim3(D_MODEL / 128, NTOK / 128), blk, 0, stream>>>(
        ctx, woT, bo, bo, bo, y1, NTOK, D_MODEL, D_MODEL);

    add_ln_kernel<float, u16, u16><<<dim3(NTOK), blk, 0, stream>>>(x, y1, g1, beta1, x2);

    gemm_bf16_kernel<1, u16><<<dim3(D_FF / 128, NTOK / 128), blk, 0, stream>>>(
        x2, w1T, b1, b1, b1, h1, NTOK, D_FF, D_MODEL);
    gemm_bf16_kernel<0, float><<<dim3(D_MODEL / 128, NTOK / 128), blk, 0, stream>>>(
        h1, w2T, b2, b2, b2, out, NTOK, D_MODEL, D_FF);

    add_ln_kernel<u16, float, float><<<dim3(NTOK), blk, 0, stream>>>(x2, out, g2, beta2, out);

    (void)in_sizes; (void)n_in; (void)out_size; (void)ws_size;
}

// Round 5
// 414.210 us; speedup vs baseline: 11.7829x; 1.0884x over previous
//
#include <hip/hip_runtime.h>
#include <math.h>
#include <stdint.h>

// EncoderLayer on MI355X — Round 4:
// - GEMMs: pipelined 128x256xBK64 kernel, 8 waves (2x4), counted vmcnt(2)
//   (never drains in-loop), A 3-deep / B 2-deep LDS buffers, chunk^row&7
//   swizzle on both stage-source and ds_read. One barrier per 32 MFMA.
// - attn: P-redistribution via v_permlane32_swap_b32 (replaces 16 ds_bpermute
//   + 16 cndmask per tile with 8 permlane swaps).

#define D_MODEL 1024
#define N_HEADS 16
#define DKH     64
#define D_FF    4096
#define BATCH   4
#define SEQ     2048
#define NTOK    (BATCH * SEQ)   // 8192
#define LN_EPS  1e-5f
#define QKV_LD  3072
#define QSCALE  0.18033688011112042f   // 0.125 * log2(e)

typedef unsigned short u16;
typedef __attribute__((ext_vector_type(8))) short bf16x8;
typedef __attribute__((ext_vector_type(4))) float f32x4;
typedef __attribute__((ext_vector_type(16))) float f32x16;

__device__ __forceinline__ u16 f2bf(float f) {
    union { float f; uint32_t u; } c; c.f = f;
    return (u16)((c.u + 0x7FFFu + ((c.u >> 16) & 1u)) >> 16);   // RNE
}
__device__ __forceinline__ float bf2f(u16 h) {
    union { uint32_t u; float f; } c; c.u = ((uint32_t)h) << 16;
    return c.f;
}

// async global->LDS, 16B/lane; lds base wave-uniform, HW writes base+lane*16
__device__ __forceinline__ void gload16(const u16* g, u16* lds) {
    __builtin_amdgcn_global_load_lds(
        (const __attribute__((address_space(1))) uint32_t*)g,
        (__attribute__((address_space(3))) uint32_t*)(uintptr_t)lds,
        16, 0, 0);
}

__device__ __forceinline__ void store_out(float* p, float v) { *p = v; }
__device__ __forceinline__ void store_out(u16* p, float v)   { *p = f2bf(v); }

// ---------------------------------------------------------------------------
// Pipelined bf16 GEMM: C[M,N] = A[M,K] @ Bt[N,K]^T + bias.
// MODE: 0 none, 1 relu, 2 qkv (region bias + Q-scale).
// BM=128, BN=256, BK=64, 512 thr = 8 waves (2M x 4N), 64x64 out per wave.
// LDS: A 3 bufs x [128][64], B 2 bufs x [256][64] (u16, chunk^row&7 swizzle).
// Schedule per K-tile t: stage B(t+1), stage A(t+2), compute(t), vmcnt(2),
// s_barrier — counted vmcnt keeps 2-6 loads in flight, never drains.
// ---------------------------------------------------------------------------
template <int MODE, typename OutT>
__global__ __launch_bounds__(512) void gemm_pipe_kernel(
    const u16* __restrict__ A, const u16* __restrict__ Bt,
    const float* __restrict__ bias, const float* __restrict__ bias2,
    const float* __restrict__ bias3, OutT* __restrict__ C,
    int M, int N, int K)
{
    __shared__ u16 lds[3 * 8192 + 2 * 16384];   // 112 KB

    const int tid  = threadIdx.x;
    const int wave = tid >> 6;
    const int lane = tid & 63;
    const int lo   = lane & 15;
    const int hi   = lane >> 4;
    const int wr   = wave >> 2;         // 0..1
    const int wc   = wave & 3;          // 0..3
    const int m0   = blockIdx.y << 7;
    const int n0   = blockIdx.x << 8;
    const int NT   = K >> 6;

    // staging: lane covers (row = base + q*8 + (lane>>3), chunk = lane&7);
    // source chunk pre-swizzled so LDS[row][c] = global[row][c ^ (row&7)]
    const int srow = lane >> 3;
    const int schk = (lane & 7) ^ srow;
    const u16* AgS = A  + (size_t)(m0 + wave * 16 + srow) * K + schk * 8;
    const u16* BgS = Bt + (size_t)(n0 + wave * 32 + srow) * K + schk * 8;
    u16* AdS = lds + wave * 1024;            // + buf*8192  + q*512
    u16* BdS = lds + 24576 + wave * 2048;    // + buf*16384 + q*512

    auto stageA = [&](int kt, int buf) {
        const u16* g = AgS + kt * 64;
        u16* d = AdS + buf * 8192;
#pragma unroll
        for (int q = 0; q < 2; ++q)
            gload16(g + (size_t)q * 8 * K, d + q * 512);
    };
    auto stageB = [&](int kt, int buf) {
        const u16* g = BgS + kt * 64;
        u16* d = BdS + buf * 16384;
#pragma unroll
        for (int q = 0; q < 4; ++q)
            gload16(g + (size_t)q * 8 * K, d + q * 512);
    };

    f32x4 acc[4][4];
#pragma unroll
    for (int i = 0; i < 4; ++i)
#pragma unroll
        for (int j = 0; j < 4; ++j)
#pragma unroll
            for (int r = 0; r < 4; ++r) acc[i][j][r] = 0.f;

    // prologue: A(0), B(0), A(1) -> wait leaves A(1)'s 2 loads in flight
    stageA(0, 0);
    stageB(0, 0);
    stageA(1, 1);
    __builtin_amdgcn_sched_barrier(0);
    asm volatile("s_waitcnt vmcnt(2)" ::: "memory");
    __builtin_amdgcn_s_barrier();
    __builtin_amdgcn_sched_barrier(0);

    for (int t = 0; t < NT; ++t) {
        int tb = t + 1; if (tb >= NT) tb = 0;
        int ta = t + 2; if (ta >= NT) ta -= NT;
        stageB(tb, (t + 1) & 1);
        stageA(ta, (t + 2) % 3);

        const u16* Ab = lds + (t % 3) * 8192;
        const u16* Bb = lds + 24576 + (t & 1) * 16384;
#pragma unroll
        for (int ks = 0; ks < 2; ++ks) {
            bf16x8 a[4], b[4];
#pragma unroll
            for (int i = 0; i < 4; ++i) {
                const int ar = wr * 64 + i * 16 + lo;
                a[i] = *(const bf16x8*)&Ab[ar * 64 + (((ks * 4 + hi) ^ (ar & 7)) << 3)];
                const int br = wc * 64 + i * 16 + lo;
                b[i] = *(const bf16x8*)&Bb[br * 64 + (((ks * 4 + hi) ^ (br & 7)) << 3)];
            }
            __builtin_amdgcn_s_setprio(1);
#pragma unroll
            for (int i = 0; i < 4; ++i)
#pragma unroll
                for (int j = 0; j < 4; ++j)
                    acc[i][j] = __builtin_amdgcn_mfma_f32_16x16x32_bf16(
                                    a[i], b[j], acc[i][j], 0, 0, 0);
            __builtin_amdgcn_s_setprio(0);
        }
        // boundary: everything except A(t+2)'s 2 loads has landed
        __builtin_amdgcn_sched_barrier(0);
        asm volatile("s_waitcnt vmcnt(2)" ::: "memory");
        __builtin_amdgcn_s_barrier();
        __builtin_amdgcn_sched_barrier(0);
    }

    // epilogue: C/D layout col=lane&15, row=(lane>>4)*4+reg
    const int crow0 = m0 + wr * 64 + hi * 4;
    const int ccol0 = n0 + wc * 64 + lo;
#pragma unroll
    for (int j = 0; j < 4; ++j) {
        const int col = ccol0 + j * 16;
        float bj;
        float sc = 1.0f;
        if (MODE == 2) {
            bj = (col < 1024) ? bias[col]
               : (col < 2048) ? bias2[col - 1024] : bias3[col - 2048];
            if (col < 1024) sc = QSCALE;
        } else {
            bj = bias[col];
        }
#pragma unroll
        for (int i = 0; i < 4; ++i)
#pragma unroll
            for (int r = 0; r < 4; ++r) {
                float v = acc[i][j][r] + bj;
                if (MODE == 1) v = fmaxf(v, 0.f);
                if (MODE == 2) v *= sc;
                store_out(&C[(size_t)(crow0 + i * 16 + r) * N + col], v);
            }
    }
}

// ---------------------------------------------------------------------------
// Flash attention, swapped QK^T on 32x32x16 MFMA (unchanged structure from
// round 3 except P-redistribution now uses v_permlane32_swap_b32).
// ---------------------------------------------------------------------------
__global__ __launch_bounds__(256, 3) void attn_mfma_kernel(
    const u16* __restrict__ QKV, u16* __restrict__ O)
{
    __shared__ u16 Klds[64 * 64];   // [kv][dk]
    __shared__ u16 Vlds[64 * 64];   // [dk][kv] (transposed)

    const int tid  = threadIdx.x;
    const int wave = tid >> 6;
    const int lane = tid & 63;
    const int l31  = lane & 31;
    const int hi5  = lane >> 5;
    const int b    = blockIdx.x >> 4;
    const int h    = blockIdx.x & 15;
    const int q0   = blockIdx.y * 128 + wave * 32;
    const size_t rowb = (size_t)b * SEQ * QKV_LD + (size_t)h * DKH;
    const u16* Qg = QKV + rowb;
    const u16* Kg = QKV + rowb + 1024;
    const u16* Vg = QKV + rowb + 2048;

    // Q as B-operand: col(q) = l31, k = 16f + 8*hi5 + e
    bf16x8 qf[4];
#pragma unroll
    for (int f = 0; f < 4; ++f)
        qf[f] = *(const bf16x8*)&Qg[(size_t)(q0 + l31) * QKV_LD + 16 * f + 8 * hi5];

    f32x16 oacc[2];
#pragma unroll
    for (int g = 0; g < 2; ++g)
#pragma unroll
        for (int r = 0; r < 16; ++r) oacc[g][r] = 0.f;
    float mrun = -1e30f, lrun = 0.f;

    // K staging via gload16 with pre-swizzled source
    const int krow = wave * 8 + (lane >> 3);
    const int kchk = ((lane & 7) ^ (lane >> 3)) << 3;
    u16* kdst = Klds + wave * 512;

    // V transpose staging: thread owns 4 kv x 4 dk
    const int vdk0 = (tid & 15) * 4;
    const int vkv  = (tid >> 4) * 4;
    const int vchk = vkv >> 3;
    const int vsub = vkv & 7;

    for (int kv0 = 0; kv0 < SEQ; kv0 += 64) {
        __syncthreads();
        gload16(Kg + (size_t)(kv0 + krow) * QKV_LD + kchk,      kdst);
        gload16(Kg + (size_t)(kv0 + krow + 32) * QKV_LD + kchk, kdst + 32 * 64);
        alignas(8) u16 e[4][4];
#pragma unroll
        for (int i = 0; i < 4; ++i)
            *(uint2*)e[i] = *(const uint2*)&Vg[(size_t)(kv0 + vkv + i) * QKV_LD + vdk0];
#pragma unroll
        for (int j = 0; j < 4; ++j) {
            alignas(8) u16 w4[4] = { e[0][j], e[1][j], e[2][j], e[3][j] };
            const int row = vdk0 + j;
            *(uint2*)&Vlds[row * 64 + ((vchk ^ (row & 7)) << 3) + vsub] = *(const uint2*)w4;
        }
        __syncthreads();

        // S^T = K·Q (exp2 units, scale folded into Q)
        f32x16 s0, s1;
#pragma unroll
        for (int r = 0; r < 16; ++r) { s0[r] = 0.f; s1[r] = 0.f; }
#pragma unroll
        for (int f = 0; f < 4; ++f) {
            const int rc = ((2 * f + hi5) ^ (l31 & 7)) << 3;
            const bf16x8 ka = *(const bf16x8*)&Klds[l31 * 64 + rc];
            const bf16x8 kb = *(const bf16x8*)&Klds[(32 + l31) * 64 + rc];
            s0 = __builtin_amdgcn_mfma_f32_32x32x16_bf16(ka, qf[f], s0, 0, 0, 0);
            s1 = __builtin_amdgcn_mfma_f32_32x32x16_bf16(kb, qf[f], s1, 0, 0, 0);
        }

        // per-lane online softmax; one cross-lane exchange for the pair max
        float tm = s0[0];
#pragma unroll
        for (int r = 1; r < 16; ++r) tm = fmaxf(tm, s0[r]);
#pragma unroll
        for (int r = 0; r < 16; ++r) tm = fmaxf(tm, s1[r]);
        tm = fmaxf(tm, __shfl_xor(tm, 32, 64));
        if (__any(tm > mrun + 8.0f)) {              // defer-max (T13)
            const float mnew = fmaxf(mrun, tm);
            const float corr = exp2f(mrun - mnew);
            lrun *= corr;
#pragma unroll
            for (int g = 0; g < 2; ++g)
#pragma unroll
                for (int r = 0; r < 16; ++r) oacc[g][r] *= corr;
            mrun = mnew;
        }
        float ls = 0.f;
#pragma unroll
        for (int r = 0; r < 16; ++r) { s0[r] = exp2f(s0[r] - mrun); ls += s0[r]; }
#pragma unroll
        for (int r = 0; r < 16; ++r) { s1[r] = exp2f(s1[r] - mrun); ls += s1[r]; }
        lrun += ls;

        // P B-frags via cvt_pk + permlane32_swap:
        // A=pk(a0,a1), B=pk(a4,a5): swap -> A'={A.lo,B.lo}=w0, B'={A.hi,B.hi}=w2
        auto mkfrag = [&](float a0, float a1, float a2, float a3,
                          float a4, float a5, float a6, float a7) -> bf16x8 {
            uint32_t A, B, C, D;
            asm("v_cvt_pk_bf16_f32 %0, %1, %2" : "=v"(A) : "v"(a0), "v"(a1));
            asm("v_cvt_pk_bf16_f32 %0, %1, %2" : "=v"(C) : "v"(a2), "v"(a3));
            asm("v_cvt_pk_bf16_f32 %0, %1, %2" : "=v"(B) : "v"(a4), "v"(a5));
            asm("v_cvt_pk_bf16_f32 %0, %1, %2" : "=v"(D) : "v"(a6), "v"(a7));
            asm volatile("v_permlane32_swap_b32 %0, %1" : "+v"(A), "+v"(B));
            asm volatile("v_permlane32_swap_b32 %0, %1" : "+v"(C), "+v"(D));
            union { uint32_t w[4]; bf16x8 v; } u;
            u.w[0] = A; u.w[1] = C; u.w[2] = B; u.w[3] = D;
            return u.v;
        };
        bf16x8 pb0 = mkfrag(s0[0], s0[1], s0[2],  s0[3],  s0[4],  s0[5],  s0[6],  s0[7]);
        bf16x8 pb1 = mkfrag(s0[8], s0[9], s0[10], s0[11], s0[12], s0[13], s0[14], s0[15]);
        bf16x8 pb2 = mkfrag(s1[0], s1[1], s1[2],  s1[3],  s1[4],  s1[5],  s1[6],  s1[7]);
        bf16x8 pb3 = mkfrag(s1[8], s1[9], s1[10], s1[11], s1[12], s1[13], s1[14], s1[15]);

        // O^T += V^T · P
#pragma unroll
        for (int f = 0; f < 4; ++f) {
            const bf16x8 pf = (f == 0) ? pb0 : (f == 1) ? pb1 : (f == 2) ? pb2 : pb3;
            const int rc = ((2 * f + hi5) ^ (l31 & 7)) << 3;
            const bf16x8 va = *(const bf16x8*)&Vlds[l31 * 64 + rc];
            const bf16x8 vb = *(const bf16x8*)&Vlds[(32 + l31) * 64 + rc];
            oacc[0] = __builtin_amdgcn_mfma_f32_32x32x16_bf16(va, pf, oacc[0], 0, 0, 0);
            oacc[1] = __builtin_amdgcn_mfma_f32_32x32x16_bf16(vb, pf, oacc[1], 0, 0, 0);
        }
    }

    lrun += __shfl_xor(lrun, 32, 64);
    const float inv = 1.0f / lrun;
    u16* Orow = O + (size_t)b * SEQ * D_MODEL + (size_t)(q0 + l31) * D_MODEL + h * DKH;
#pragma unroll
    for (int g = 0; g < 2; ++g)
#pragma unroll
        for (int rp = 0; rp < 8; ++rp) {
            const int r = rp * 2;
            const float v0 = oacc[g][r] * inv;
            const float v1 = oacc[g][r + 1] * inv;
            uint32_t pk;
            asm("v_cvt_pk_bf16_f32 %0, %1, %2" : "=v"(pk) : "v"(v0), "v"(v1));
            const int d = 32 * g + (r & 3) + 8 * (r >> 2) + 4 * hi5;
            *(uint32_t*)&Orow[d] = pk;
        }
}

// ---------------------------------------------------------------------------
// W[K][N] f32 -> Wt[N][K] bf16 (tiled 32x32 transpose)
// ---------------------------------------------------------------------------
__global__ __launch_bounds__(256) void transpose_w_kernel(
    const float* __restrict__ W, u16* __restrict__ Wt, int K, int N)
{
    __shared__ float t[32][33];
    const int n0 = blockIdx.x << 5;
    const int k0 = blockIdx.y << 5;
    const int tx = threadIdx.x & 31;
    const int ty = threadIdx.x >> 5;
#pragma unroll
    for (int i = 0; i < 4; ++i)
        t[ty + i * 8][tx] = W[(size_t)(k0 + ty + i * 8) * N + n0 + tx];
    __syncthreads();
#pragma unroll
    for (int i = 0; i < 4; ++i)
        Wt[(size_t)(n0 + ty + i * 8) * K + k0 + tx] = f2bf(t[tx][ty + i * 8]);
}

// f32 -> bf16 bulk convert, 8 elems/thread
__global__ __launch_bounds__(256) void cvt_kernel(
    const float* __restrict__ src, u16* __restrict__ dst)
{
    const size_t i = ((size_t)blockIdx.x * 256 + threadIdx.x) * 8;
    const float4 a = *(const float4*)&src[i];
    const float4 b = *(const float4*)&src[i + 4];
    alignas(16) u16 e[8] = { f2bf(a.x), f2bf(a.y), f2bf(a.z), f2bf(a.w),
                             f2bf(b.x), f2bf(b.y), f2bf(b.z), f2bf(b.w) };
    *(int4*)&dst[i] = *(const int4*)e;
}

// ---------------------------------------------------------------------------
// out = LayerNorm(X + Y)*gamma + beta; mixed dtypes. One block per row.
// ---------------------------------------------------------------------------
__device__ __forceinline__ float4 ld4(const float* p) { return *(const float4*)p; }
__device__ __forceinline__ float4 ld4(const u16* p) {
    alignas(8) u16 e[4];
    *(uint2*)e = *(const uint2*)p;
    return make_float4(bf2f(e[0]), bf2f(e[1]), bf2f(e[2]), bf2f(e[3]));
}
__device__ __forceinline__ void st4(float* p, float4 v) { *(float4*)p = v; }
__device__ __forceinline__ void st4(u16* p, float4 v) {
    alignas(8) u16 e[4] = { f2bf(v.x), f2bf(v.y), f2bf(v.z), f2bf(v.w) };
    *(uint2*)p = *(const uint2*)e;
}

template <typename XT, typename YT, typename OT>
__global__ __launch_bounds__(256) void add_ln_kernel(
    const XT* __restrict__ X, const YT* __restrict__ Y,
    const float* __restrict__ gamma, const float* __restrict__ beta,
    OT* __restrict__ Out)
{
    const int row = blockIdx.x;
    const int i0  = threadIdx.x << 2;
    const float4 xv = ld4(X + (size_t)row * D_MODEL + i0);
    const float4 yv = ld4(Y + (size_t)row * D_MODEL + i0);
    const float4 v  = make_float4(xv.x + yv.x, xv.y + yv.y, xv.z + yv.z, xv.w + yv.w);

    float s1 = v.x + v.y + v.z + v.w;
    float s2 = v.x * v.x + v.y * v.y + v.z * v.z + v.w * v.w;
#pragma unroll
    for (int off = 32; off > 0; off >>= 1) {
        s1 += __shfl_xor(s1, off, 64);
        s2 += __shfl_xor(s2, off, 64);
    }
    __shared__ float red[8];
    const int wid = threadIdx.x >> 6;
    if ((threadIdx.x & 63) == 0) { red[wid] = s1; red[wid + 4] = s2; }
    __syncthreads();
    s1 = red[0] + red[1] + red[2] + red[3];
    s2 = red[4] + red[5] + red[6] + red[7];

    const float mu   = s1 * (1.0f / D_MODEL);
    const float var  = s2 * (1.0f / D_MODEL) - mu * mu;
    const float rstd = rsqrtf(var + LN_EPS);

    const float4 g  = *(const float4*)(gamma + i0);
    const float4 bb = *(const float4*)(beta + i0);
    float4 ov;
    ov.x = (v.x - mu) * rstd * g.x + bb.x;
    ov.y = (v.y - mu) * rstd * g.y + bb.y;
    ov.z = (v.z - mu) * rstd * g.z + bb.z;
    ov.w = (v.w - mu) * rstd * g.w + bb.w;
    st4(Out + (size_t)row * D_MODEL + i0, ov);
}

// ---------------------------------------------------------------------------
extern "C" void kernel_launch(void* const* d_in, const int* in_sizes, int n_in,
                              void* d_out, int out_size, void* d_ws, size_t ws_size,
                              hipStream_t stream)
{
    const float* x     = (const float*)d_in[0];
    const float* Wq    = (const float*)d_in[1];
    const float* bq    = (const float*)d_in[2];
    const float* Wk    = (const float*)d_in[3];
    const float* bk    = (const float*)d_in[4];
    const float* Wv    = (const float*)d_in[5];
    const float* bv    = (const float*)d_in[6];
    const float* Wo    = (const float*)d_in[7];
    const float* bo    = (const float*)d_in[8];
    const float* W1    = (const float*)d_in[9];
    const float* b1    = (const float*)d_in[10];
    const float* W2    = (const float*)d_in[11];
    const float* b2    = (const float*)d_in[12];
    const float* g1    = (const float*)d_in[13];
    const float* beta1 = (const float*)d_in[14];
    const float* g2    = (const float*)d_in[15];
    const float* beta2 = (const float*)d_in[16];
    float* out = (float*)d_out;

    const size_t TOKD = (size_t)NTOK * D_MODEL;
    u16* xb    = (u16*)d_ws;
    u16* wqkvT = xb + TOKD;                              // [3072][1024]
    u16* woT   = wqkvT + (size_t)3 * D_MODEL * D_MODEL;
    u16* w1T   = woT + (size_t)D_MODEL * D_MODEL;        // [4096][1024]
    u16* w2T   = w1T + (size_t)D_MODEL * D_FF;           // [1024][4096]
    u16* qkv   = w2T + (size_t)D_FF * D_MODEL;           // [NTOK][3072]
    u16* ctx   = qkv + (size_t)NTOK * QKV_LD;
    u16* y1    = ctx + TOKD;
    u16* x2    = y1;                                     // LN1 in place
    u16* h1    = qkv;                                    // spans qkv+ctx

    const dim3 blk(256);
    const dim3 blk5(512);

    cvt_kernel<<<dim3(TOKD / 2048), blk, 0, stream>>>(x, xb);
    transpose_w_kernel<<<dim3(D_MODEL / 32, D_MODEL / 32), blk, 0, stream>>>(Wq, wqkvT, D_MODEL, D_MODEL);
    transpose_w_kernel<<<dim3(D_MODEL / 32, D_MODEL / 32), blk, 0, stream>>>(Wk, wqkvT + (size_t)D_MODEL * D_MODEL, D_MODEL, D_MODEL);
    transpose_w_kernel<<<dim3(D_MODEL / 32, D_MODEL / 32), blk, 0, stream>>>(Wv, wqkvT + (size_t)2 * D_MODEL * D_MODEL, D_MODEL, D_MODEL);
    transpose_w_kernel<<<dim3(D_MODEL / 32, D_MODEL / 32), blk, 0, stream>>>(Wo, woT, D_MODEL, D_MODEL);
    transpose_w_kernel<<<dim3(D_FF / 32,    D_MODEL / 32), blk, 0, stream>>>(W1, w1T, D_MODEL, D_FF);
    transpose_w_kernel<<<dim3(D_MODEL / 32, D_FF / 32),    blk, 0, stream>>>(W2, w2T, D_FF, D_MODEL);

    // fused QKV projection (Q pre-scaled for exp2 softmax)
    gemm_pipe_kernel<2, u16><<<dim3(QKV_LD / 256, NTOK / 128), blk5, 0, stream>>>(
        xb, wqkvT, bq, bk, bv, qkv, NTOK, QKV_LD, D_MODEL);

    attn_mfma_kernel<<<dim3(BATCH * N_HEADS, SEQ / 128), blk, 0, stream>>>(qkv, ctx);

    gemm_pipe_kernel<0, u16><<<dim3(D_MODEL / 256, NTOK / 128), blk5, 0, stream>>>(
        ctx, woT, bo, bo, bo, y1, NTOK, D_MODEL, D_MODEL);

    add_ln_kernel<float, u16, u16><<<dim3(NTOK), blk, 0, stream>>>(x, y1, g1, beta1, x2);

    gemm_pipe_kernel<1, u16><<<dim3(D_FF / 256, NTOK / 128), blk5, 0, stream>>>(
        x2, w1T, b1, b1, b1, h1, NTOK, D_FF, D_MODEL);
    gemm_pipe_kernel<0, float><<<dim3(D_MODEL / 256, NTOK / 128), blk5, 0, stream>>>(
        h1, w2T, b2, b2, b2, out, NTOK, D_MODEL, D_FF);

    add_ln_kernel<u16, float, float><<<dim3(NTOK), blk, 0, stream>>>(x2, out, g2, beta2, out);

    (void)in_sizes; (void)n_in; (void)out_size; (void)ws_size;
}

// Round 6
// 407.707 us; speedup vs baseline: 11.9709x; 1.0160x over previous
//
#include <hip/hip_runtime.h>
#include <math.h>
#include <stdint.h>

// EncoderLayer on MI355X — Round 5:
// - attn: double-buffered K/V (issue-early/write-late T14), one barrier/tile,
//   tree max/sum reductions, occupancy 4 waves/SIMD.
// - GEMM: unchanged pipeline + bijective XCD-aware block swizzle (T1).

#define D_MODEL 1024
#define N_HEADS 16
#define DKH     64
#define D_FF    4096
#define BATCH   4
#define SEQ     2048
#define NTOK    (BATCH * SEQ)   // 8192
#define LN_EPS  1e-5f
#define QKV_LD  3072
#define QSCALE  0.18033688011112042f   // 0.125 * log2(e)

typedef unsigned short u16;
typedef __attribute__((ext_vector_type(8))) short bf16x8;
typedef __attribute__((ext_vector_type(4))) float f32x4;
typedef __attribute__((ext_vector_type(16))) float f32x16;

__device__ __forceinline__ u16 f2bf(float f) {
    union { float f; uint32_t u; } c; c.f = f;
    return (u16)((c.u + 0x7FFFu + ((c.u >> 16) & 1u)) >> 16);   // RNE
}
__device__ __forceinline__ float bf2f(u16 h) {
    union { uint32_t u; float f; } c; c.u = ((uint32_t)h) << 16;
    return c.f;
}

// async global->LDS, 16B/lane; lds base wave-uniform, HW writes base+lane*16
__device__ __forceinline__ void gload16(const u16* g, u16* lds) {
    __builtin_amdgcn_global_load_lds(
        (const __attribute__((address_space(1))) uint32_t*)g,
        (__attribute__((address_space(3))) uint32_t*)(uintptr_t)lds,
        16, 0, 0);
}

__device__ __forceinline__ void store_out(float* p, float v) { *p = v; }
__device__ __forceinline__ void store_out(u16* p, float v)   { *p = f2bf(v); }

// ---------------------------------------------------------------------------
// Pipelined bf16 GEMM: C[M,N] = A[M,K] @ Bt[N,K]^T + bias.
// MODE: 0 none, 1 relu, 2 qkv (region bias + Q-scale).
// BM=128, BN=256, BK=64, 512 thr = 8 waves (2M x 4N), 64x64 out per wave.
// LDS: A 3 bufs, B 2 bufs, chunk^row&7 swizzle. vmcnt(2) at boundaries.
// Block index XCD-swizzled: XCD x owns a contiguous 1/8 of the grid.
// ---------------------------------------------------------------------------
template <int MODE, typename OutT>
__global__ __launch_bounds__(512) void gemm_pipe_kernel(
    const u16* __restrict__ A, const u16* __restrict__ Bt,
    const float* __restrict__ bias, const float* __restrict__ bias2,
    const float* __restrict__ bias3, OutT* __restrict__ C,
    int M, int N, int K)
{
    __shared__ u16 lds[3 * 8192 + 2 * 16384];   // 112 KB

    const int tid  = threadIdx.x;
    const int wave = tid >> 6;
    const int lane = tid & 63;
    const int lo   = lane & 15;
    const int hi   = lane >> 4;
    const int wr   = wave >> 2;         // 0..1
    const int wc   = wave & 3;          // 0..3

    // XCD-aware swizzle (nwg always %8==0 here): XCD x -> contiguous chunk
    const int gx  = gridDim.x;
    const int nwg = gx * gridDim.y;
    int bid = blockIdx.y * gx + blockIdx.x;
    bid = (bid & 7) * (nwg >> 3) + (bid >> 3);
    const int m0 = (bid / gx) << 7;
    const int n0 = (bid % gx) << 8;
    const int NT = K >> 6;

    // staging: lane covers (row = base + q*8 + (lane>>3), chunk = lane&7);
    // source chunk pre-swizzled so LDS[row][c] = global[row][c ^ (row&7)]
    const int srow = lane >> 3;
    const int schk = (lane & 7) ^ srow;
    const u16* AgS = A  + (size_t)(m0 + wave * 16 + srow) * K + schk * 8;
    const u16* BgS = Bt + (size_t)(n0 + wave * 32 + srow) * K + schk * 8;
    u16* AdS = lds + wave * 1024;            // + buf*8192  + q*512
    u16* BdS = lds + 24576 + wave * 2048;    // + buf*16384 + q*512

    auto stageA = [&](int kt, int buf) {
        const u16* g = AgS + kt * 64;
        u16* d = AdS + buf * 8192;
#pragma unroll
        for (int q = 0; q < 2; ++q)
            gload16(g + (size_t)q * 8 * K, d + q * 512);
    };
    auto stageB = [&](int kt, int buf) {
        const u16* g = BgS + kt * 64;
        u16* d = BdS + buf * 16384;
#pragma unroll
        for (int q = 0; q < 4; ++q)
            gload16(g + (size_t)q * 8 * K, d + q * 512);
    };

    f32x4 acc[4][4];
#pragma unroll
    for (int i = 0; i < 4; ++i)
#pragma unroll
        for (int j = 0; j < 4; ++j)
#pragma unroll
            for (int r = 0; r < 4; ++r) acc[i][j][r] = 0.f;

    // prologue: A(0), B(0), A(1) -> wait leaves A(1)'s 2 loads in flight
    stageA(0, 0);
    stageB(0, 0);
    stageA(1, 1);
    __builtin_amdgcn_sched_barrier(0);
    asm volatile("s_waitcnt vmcnt(2)" ::: "memory");
    __builtin_amdgcn_s_barrier();
    __builtin_amdgcn_sched_barrier(0);

    for (int t = 0; t < NT; ++t) {
        int tb = t + 1; if (tb >= NT) tb = 0;
        int ta = t + 2; if (ta >= NT) ta -= NT;
        stageB(tb, (t + 1) & 1);
        stageA(ta, (t + 2) % 3);

        const u16* Ab = lds + (t % 3) * 8192;
        const u16* Bb = lds + 24576 + (t & 1) * 16384;
#pragma unroll
        for (int ks = 0; ks < 2; ++ks) {
            bf16x8 a[4], b[4];
#pragma unroll
            for (int i = 0; i < 4; ++i) {
                const int ar = wr * 64 + i * 16 + lo;
                a[i] = *(const bf16x8*)&Ab[ar * 64 + (((ks * 4 + hi) ^ (ar & 7)) << 3)];
                const int br = wc * 64 + i * 16 + lo;
                b[i] = *(const bf16x8*)&Bb[br * 64 + (((ks * 4 + hi) ^ (br & 7)) << 3)];
            }
            __builtin_amdgcn_s_setprio(1);
#pragma unroll
            for (int i = 0; i < 4; ++i)
#pragma unroll
                for (int j = 0; j < 4; ++j)
                    acc[i][j] = __builtin_amdgcn_mfma_f32_16x16x32_bf16(
                                    a[i], b[j], acc[i][j], 0, 0, 0);
            __builtin_amdgcn_s_setprio(0);
        }
        __builtin_amdgcn_sched_barrier(0);
        asm volatile("s_waitcnt vmcnt(2)" ::: "memory");
        __builtin_amdgcn_s_barrier();
        __builtin_amdgcn_sched_barrier(0);
    }

    // epilogue: C/D layout col=lane&15, row=(lane>>4)*4+reg
    const int crow0 = m0 + wr * 64 + hi * 4;
    const int ccol0 = n0 + wc * 64 + lo;
#pragma unroll
    for (int j = 0; j < 4; ++j) {
        const int col = ccol0 + j * 16;
        float bj;
        float sc = 1.0f;
        if (MODE == 2) {
            bj = (col < 1024) ? bias[col]
               : (col < 2048) ? bias2[col - 1024] : bias3[col - 2048];
            if (col < 1024) sc = QSCALE;
        } else {
            bj = bias[col];
        }
#pragma unroll
        for (int i = 0; i < 4; ++i)
#pragma unroll
            for (int r = 0; r < 4; ++r) {
                float v = acc[i][j][r] + bj;
                if (MODE == 1) v = fmaxf(v, 0.f);
                if (MODE == 2) v *= sc;
                store_out(&C[(size_t)(crow0 + i * 16 + r) * N + col], v);
            }
    }
}

// ---------------------------------------------------------------------------
// Flash attention, swapped QK^T on 32x32x16 MFMA. Double-buffered K/V:
// stage(t+1) issued before compute(t), V LDS-write deferred past softmax,
// ONE barrier per tile. Tree max/sum reductions.
// ---------------------------------------------------------------------------
__global__ __launch_bounds__(256, 4) void attn_mfma_kernel(
    const u16* __restrict__ QKV, u16* __restrict__ O)
{
    __shared__ u16 Klds[2][64 * 64];   // [kv][dk], chunk-swizzled content
    __shared__ u16 Vlds[2][64 * 64];   // [dk][kv] transposed, chunk-swizzled

    const int tid  = threadIdx.x;
    const int wave = tid >> 6;
    const int lane = tid & 63;
    const int l31  = lane & 31;
    const int hi5  = lane >> 5;
    const int b    = blockIdx.x >> 4;
    const int h    = blockIdx.x & 15;
    const int q0   = blockIdx.y * 128 + wave * 32;
    const size_t rowb = (size_t)b * SEQ * QKV_LD + (size_t)h * DKH;
    const u16* Qg = QKV + rowb;
    const u16* Kg = QKV + rowb + 1024;
    const u16* Vg = QKV + rowb + 2048;

    // Q as B-operand: col(q) = l31, k = 16f + 8*hi5 + e
    bf16x8 qf[4];
#pragma unroll
    for (int f = 0; f < 4; ++f)
        qf[f] = *(const bf16x8*)&Qg[(size_t)(q0 + l31) * QKV_LD + 16 * f + 8 * hi5];

    f32x16 oacc[2];
#pragma unroll
    for (int g = 0; g < 2; ++g)
#pragma unroll
        for (int r = 0; r < 16; ++r) oacc[g][r] = 0.f;
    float mrun = -1e30f, lrun = 0.f;

    // K staging via gload16 with pre-swizzled source
    const int krow = wave * 8 + (lane >> 3);
    const int kchk = ((lane & 7) ^ (lane >> 3)) << 3;

    // V transpose staging: thread owns 4 kv x 4 dk
    const int vdk0 = (tid & 15) * 4;
    const int vkv  = (tid >> 4) * 4;
    const int vchk = vkv >> 3;
    const int vsub = vkv & 7;

    alignas(8) u16 e[4][4];   // in-flight V block (issue-early, write-late)

    auto stageK = [&](int kv0, int buf) {
        u16* kdst = &Klds[buf][wave * 512];
        gload16(Kg + (size_t)(kv0 + krow) * QKV_LD + kchk,      kdst);
        gload16(Kg + (size_t)(kv0 + krow + 32) * QKV_LD + kchk, kdst + 32 * 64);
    };
    auto loadV = [&](int kv0) {
#pragma unroll
        for (int i = 0; i < 4; ++i)
            *(uint2*)e[i] = *(const uint2*)&Vg[(size_t)(kv0 + vkv + i) * QKV_LD + vdk0];
    };
    auto writeV = [&](int buf) {
#pragma unroll
        for (int j = 0; j < 4; ++j) {
            alignas(8) u16 w4[4] = { e[0][j], e[1][j], e[2][j], e[3][j] };
            const int row = vdk0 + j;
            *(uint2*)&Vlds[buf][row * 64 + ((vchk ^ (row & 7)) << 3) + vsub] =
                *(const uint2*)w4;
        }
    };

    // prologue: tile 0 into buf 0
    stageK(0, 0);
    loadV(0);
    writeV(0);
    __syncthreads();

    constexpr int NTILES = SEQ / 64;
    for (int t = 0; t < NTILES; ++t) {
        const int cur = t & 1, nxt = cur ^ 1;
        if (t + 1 < NTILES) {              // issue next tile's loads NOW
            stageK((t + 1) * 64, nxt);
            loadV((t + 1) * 64);
        }

        // S^T = K·Q (exp2 units, scale folded into Q)
        f32x16 s0, s1;
#pragma unroll
        for (int r = 0; r < 16; ++r) { s0[r] = 0.f; s1[r] = 0.f; }
#pragma unroll
        for (int f = 0; f < 4; ++f) {
            const int rc = ((2 * f + hi5) ^ (l31 & 7)) << 3;
            const bf16x8 ka = *(const bf16x8*)&Klds[cur][l31 * 64 + rc];
            const bf16x8 kb = *(const bf16x8*)&Klds[cur][(32 + l31) * 64 + rc];
            s0 = __builtin_amdgcn_mfma_f32_32x32x16_bf16(ka, qf[f], s0, 0, 0, 0);
            s1 = __builtin_amdgcn_mfma_f32_32x32x16_bf16(kb, qf[f], s1, 0, 0, 0);
        }

        // tree max (log depth), one cross-lane exchange for the pair
        float mx[16];
#pragma unroll
        for (int r = 0; r < 16; ++r) mx[r] = fmaxf(s0[r], s1[r]);
#pragma unroll
        for (int off = 8; off >= 1; off >>= 1)
#pragma unroll
            for (int r = 0; r < off; ++r) mx[r] = fmaxf(mx[r], mx[r + off]);
        float tm = fmaxf(mx[0], __shfl_xor(mx[0], 32, 64));
        if (__any(tm > mrun + 8.0f)) {              // defer-max (T13)
            const float mnew = fmaxf(mrun, tm);
            const float corr = exp2f(mrun - mnew);
            lrun *= corr;
#pragma unroll
            for (int g = 0; g < 2; ++g)
#pragma unroll
                for (int r = 0; r < 16; ++r) oacc[g][r] *= corr;
            mrun = mnew;
        }
        float sm[16];
#pragma unroll
        for (int r = 0; r < 16; ++r) {
            s0[r] = exp2f(s0[r] - mrun);
            s1[r] = exp2f(s1[r] - mrun);
            sm[r] = s0[r] + s1[r];
        }
#pragma unroll
        for (int off = 8; off >= 1; off >>= 1)
#pragma unroll
            for (int r = 0; r < off; ++r) sm[r] += sm[r + off];
        lrun += sm[0];

        if (t + 1 < NTILES) writeV(nxt);   // vmcnt wait lands here, post-softmax

        // P B-frags via cvt_pk + permlane32_swap
        auto mkfrag = [&](float a0, float a1, float a2, float a3,
                          float a4, float a5, float a6, float a7) -> bf16x8 {
            uint32_t A, B, C, D;
            asm("v_cvt_pk_bf16_f32 %0, %1, %2" : "=v"(A) : "v"(a0), "v"(a1));
            asm("v_cvt_pk_bf16_f32 %0, %1, %2" : "=v"(C) : "v"(a2), "v"(a3));
            asm("v_cvt_pk_bf16_f32 %0, %1, %2" : "=v"(B) : "v"(a4), "v"(a5));
            asm("v_cvt_pk_bf16_f32 %0, %1, %2" : "=v"(D) : "v"(a6), "v"(a7));
            asm volatile("v_permlane32_swap_b32 %0, %1" : "+v"(A), "+v"(B));
            asm volatile("v_permlane32_swap_b32 %0, %1" : "+v"(C), "+v"(D));
            union { uint32_t w[4]; bf16x8 v; } u;
            u.w[0] = A; u.w[1] = C; u.w[2] = B; u.w[3] = D;
            return u.v;
        };
        bf16x8 pb0 = mkfrag(s0[0], s0[1], s0[2],  s0[3],  s0[4],  s0[5],  s0[6],  s0[7]);
        bf16x8 pb1 = mkfrag(s0[8], s0[9], s0[10], s0[11], s0[12], s0[13], s0[14], s0[15]);
        bf16x8 pb2 = mkfrag(s1[0], s1[1], s1[2],  s1[3],  s1[4],  s1[5],  s1[6],  s1[7]);
        bf16x8 pb3 = mkfrag(s1[8], s1[9], s1[10], s1[11], s1[12], s1[13], s1[14], s1[15]);

        // O^T += V^T · P
#pragma unroll
        for (int f = 0; f < 4; ++f) {
            const bf16x8 pf = (f == 0) ? pb0 : (f == 1) ? pb1 : (f == 2) ? pb2 : pb3;
            const int rc = ((2 * f + hi5) ^ (l31 & 7)) << 3;
            const bf16x8 va = *(const bf16x8*)&Vlds[cur][l31 * 64 + rc];
            const bf16x8 vb = *(const bf16x8*)&Vlds[cur][(32 + l31) * 64 + rc];
            oacc[0] = __builtin_amdgcn_mfma_f32_32x32x16_bf16(va, pf, oacc[0], 0, 0, 0);
            oacc[1] = __builtin_amdgcn_mfma_f32_32x32x16_bf16(vb, pf, oacc[1], 0, 0, 0);
        }
        __syncthreads();   // nxt buffers ready; cur reads done before next overwrite
    }

    lrun += __shfl_xor(lrun, 32, 64);
    const float inv = 1.0f / lrun;
    u16* Orow = O + (size_t)b * SEQ * D_MODEL + (size_t)(q0 + l31) * D_MODEL + h * DKH;
#pragma unroll
    for (int g = 0; g < 2; ++g)
#pragma unroll
        for (int rp = 0; rp < 8; ++rp) {
            const int r = rp * 2;
            const float v0 = oacc[g][r] * inv;
            const float v1 = oacc[g][r + 1] * inv;
            uint32_t pk;
            asm("v_cvt_pk_bf16_f32 %0, %1, %2" : "=v"(pk) : "v"(v0), "v"(v1));
            const int d = 32 * g + (r & 3) + 8 * (r >> 2) + 4 * hi5;
            *(uint32_t*)&Orow[d] = pk;
        }
}

// ---------------------------------------------------------------------------
// W[K][N] f32 -> Wt[N][K] bf16 (tiled 32x32 transpose)
// ---------------------------------------------------------------------------
__global__ __launch_bounds__(256) void transpose_w_kernel(
    const float* __restrict__ W, u16* __restrict__ Wt, int K, int N)
{
    __shared__ float t[32][33];
    const int n0 = blockIdx.x << 5;
    const int k0 = blockIdx.y << 5;
    const int tx = threadIdx.x & 31;
    const int ty = threadIdx.x >> 5;
#pragma unroll
    for (int i = 0; i < 4; ++i)
        t[ty + i * 8][tx] = W[(size_t)(k0 + ty + i * 8) * N + n0 + tx];
    __syncthreads();
#pragma unroll
    for (int i = 0; i < 4; ++i)
        Wt[(size_t)(n0 + ty + i * 8) * K + k0 + tx] = f2bf(t[tx][ty + i * 8]);
}

// f32 -> bf16 bulk convert, 8 elems/thread
__global__ __launch_bounds__(256) void cvt_kernel(
    const float* __restrict__ src, u16* __restrict__ dst)
{
    const size_t i = ((size_t)blockIdx.x * 256 + threadIdx.x) * 8;
    const float4 a = *(const float4*)&src[i];
    const float4 b = *(const float4*)&src[i + 4];
    alignas(16) u16 e[8] = { f2bf(a.x), f2bf(a.y), f2bf(a.z), f2bf(a.w),
                             f2bf(b.x), f2bf(b.y), f2bf(b.z), f2bf(b.w) };
    *(int4*)&dst[i] = *(const int4*)e;
}

// ---------------------------------------------------------------------------
// out = LayerNorm(X + Y)*gamma + beta; mixed dtypes. One block per row.
// ---------------------------------------------------------------------------
__device__ __forceinline__ float4 ld4(const float* p) { return *(const float4*)p; }
__device__ __forceinline__ float4 ld4(const u16* p) {
    alignas(8) u16 e[4];
    *(uint2*)e = *(const uint2*)p;
    return make_float4(bf2f(e[0]), bf2f(e[1]), bf2f(e[2]), bf2f(e[3]));
}
__device__ __forceinline__ void st4(float* p, float4 v) { *(float4*)p = v; }
__device__ __forceinline__ void st4(u16* p, float4 v) {
    alignas(8) u16 e[4] = { f2bf(v.x), f2bf(v.y), f2bf(v.z), f2bf(v.w) };
    *(uint2*)p = *(const uint2*)e;
}

template <typename XT, typename YT, typename OT>
__global__ __launch_bounds__(256) void add_ln_kernel(
    const XT* __restrict__ X, const YT* __restrict__ Y,
    const float* __restrict__ gamma, const float* __restrict__ beta,
    OT* __restrict__ Out)
{
    const int row = blockIdx.x;
    const int i0  = threadIdx.x << 2;
    const float4 xv = ld4(X + (size_t)row * D_MODEL + i0);
    const float4 yv = ld4(Y + (size_t)row * D_MODEL + i0);
    const float4 v  = make_float4(xv.x + yv.x, xv.y + yv.y, xv.z + yv.z, xv.w + yv.w);

    float s1 = v.x + v.y + v.z + v.w;
    float s2 = v.x * v.x + v.y * v.y + v.z * v.z + v.w * v.w;
#pragma unroll
    for (int off = 32; off > 0; off >>= 1) {
        s1 += __shfl_xor(s1, off, 64);
        s2 += __shfl_xor(s2, off, 64);
    }
    __shared__ float red[8];
    const int wid = threadIdx.x >> 6;
    if ((threadIdx.x & 63) == 0) { red[wid] = s1; red[wid + 4] = s2; }
    __syncthreads();
    s1 = red[0] + red[1] + red[2] + red[3];
    s2 = red[4] + red[5] + red[6] + red[7];

    const float mu   = s1 * (1.0f / D_MODEL);
    const float var  = s2 * (1.0f / D_MODEL) - mu * mu;
    const float rstd = rsqrtf(var + LN_EPS);

    const float4 g  = *(const float4*)(gamma + i0);
    const float4 bb = *(const float4*)(beta + i0);
    float4 ov;
    ov.x = (v.x - mu) * rstd * g.x + bb.x;
    ov.y = (v.y - mu) * rstd * g.y + bb.y;
    ov.z = (v.z - mu) * rstd * g.z + bb.z;
    ov.w = (v.w - mu) * rstd * g.w + bb.w;
    st4(Out + (size_t)row * D_MODEL + i0, ov);
}

// ---------------------------------------------------------------------------
extern "C" void kernel_launch(void* const* d_in, const int* in_sizes, int n_in,
                              void* d_out, int out_size, void* d_ws, size_t ws_size,
                              hipStream_t stream)
{
    const float* x     = (const float*)d_in[0];
    const float* Wq    = (const float*)d_in[1];
    const float* bq    = (const float*)d_in[2];
    const float* Wk    = (const float*)d_in[3];
    const float* bk    = (const float*)d_in[4];
    const float* Wv    = (const float*)d_in[5];
    const float* bv    = (const float*)d_in[6];
    const float* Wo    = (const float*)d_in[7];
    const float* bo    = (const float*)d_in[8];
    const float* W1    = (const float*)d_in[9];
    const float* b1    = (const float*)d_in[10];
    const float* W2    = (const float*)d_in[11];
    const float* b2    = (const float*)d_in[12];
    const float* g1    = (const float*)d_in[13];
    const float* beta1 = (const float*)d_in[14];
    const float* g2    = (const float*)d_in[15];
    const float* beta2 = (const float*)d_in[16];
    float* out = (float*)d_out;

    const size_t TOKD = (size_t)NTOK * D_MODEL;
    u16* xb    = (u16*)d_ws;
    u16* wqkvT = xb + TOKD;                              // [3072][1024]
    u16* woT   = wqkvT + (size_t)3 * D_MODEL * D_MODEL;
    u16* w1T   = woT + (size_t)D_MODEL * D_MODEL;        // [4096][1024]
    u16* w2T   = w1T + (size_t)D_MODEL * D_FF;           // [1024][4096]
    u16* qkv   = w2T + (size_t)D_FF * D_MODEL;           // [NTOK][3072]
    u16* ctx   = qkv + (size_t)NTOK * QKV_LD;
    u16* y1    = ctx + TOKD;
    u16* x2    = y1;                                     // LN1 in place
    u16* h1    = qkv;                                    // spans qkv+ctx

    const dim3 blk(256);
    const dim3 blk5(512);

    cvt_kernel<<<dim3(TOKD / 2048), blk, 0, stream>>>(x, xb);
    transpose_w_kernel<<<dim3(D_MODEL / 32, D_MODEL / 32), blk, 0, stream>>>(Wq, wqkvT, D_MODEL, D_MODEL);
    transpose_w_kernel<<<dim3(D_MODEL / 32, D_MODEL / 32), blk, 0, stream>>>(Wk, wqkvT + (size_t)D_MODEL * D_MODEL, D_MODEL, D_MODEL);
    transpose_w_kernel<<<dim3(D_MODEL / 32, D_MODEL / 32), blk, 0, stream>>>(Wv, wqkvT + (size_t)2 * D_MODEL * D_MODEL, D_MODEL, D_MODEL);
    transpose_w_kernel<<<dim3(D_MODEL / 32, D_MODEL / 32), blk, 0, stream>>>(Wo, woT, D_MODEL, D_MODEL);
    transpose_w_kernel<<<dim3(D_FF / 32,    D_MODEL / 32), blk, 0, stream>>>(W1, w1T, D_MODEL, D_FF);
    transpose_w_kernel<<<dim3(D_MODEL / 32, D_FF / 32),    blk, 0, stream>>>(W2, w2T, D_FF, D_MODEL);

    // fused QKV projection (Q pre-scaled for exp2 softmax)
    gemm_pipe_kernel<2, u16><<<dim3(QKV_LD / 256, NTOK / 128), blk5, 0, stream>>>(
        xb, wqkvT, bq, bk, bv, qkv, NTOK, QKV_LD, D_MODEL);

    attn_mfma_kernel<<<dim3(BATCH * N_HEADS, SEQ / 128), blk, 0, stream>>>(qkv, ctx);

    gemm_pipe_kernel<0, u16><<<dim3(D_MODEL / 256, NTOK / 128), blk5, 0, stream>>>(
        ctx, woT, bo, bo, bo, y1, NTOK, D_MODEL, D_MODEL);

    add_ln_kernel<float, u16, u16><<<dim3(NTOK), blk, 0, stream>>>(x, y1, g1, beta1, x2);

    gemm_pipe_kernel<1, u16><<<dim3(D_FF / 256, NTOK / 128), blk5, 0, stream>>>(
        x2, w1T, b1, b1, b1, h1, NTOK, D_FF, D_MODEL);
    gemm_pipe_kernel<0, float><<<dim3(D_MODEL / 256, NTOK / 128), blk5, 0, stream>>>(
        h1, w2T, b2, b2, b2, out, NTOK, D_MODEL, D_FF);

    add_ln_kernel<u16, float, float><<<dim3(NTOK), blk, 0, stream>>>(x2, out, g2, beta2, out);

    (void)in_sizes; (void)n_in; (void)out_size; (void)ws_size;
}